// Round 1
// baseline (2004.131 us; speedup 1.0000x reference)
//
#include <hip/hip_runtime.h>

#define N_NODES 50000
#define N_EDGES 800000
#define ETOT (N_EDGES + N_NODES)   // edges + self loops = 850000
#define G_GRAPHS 256
#define F_IN 128
#define H1 12
#define D1 32
#define C1 (H1*D1)   // 384
#define C2 64
#define NEG 0.2f

// ---------- helpers ----------
__device__ __forceinline__ unsigned fkey(float f){
  unsigned b = __float_as_uint(f);
  return (b & 0x80000000u) ? ~b : (b | 0x80000000u);
}
__device__ __forceinline__ float funkey(unsigned u){
  return (u & 0x80000000u) ? __uint_as_float(u ^ 0x80000000u) : __uint_as_float(~u);
}
__device__ __forceinline__ float lrelu(float x){ return x > 0.f ? x : NEG*x; }

// ---------- fp32 tiled GEMM: C[M,N] = A[M,K] @ B[K,N] ----------
// requires K % BK == 0 and N % BN == 0 (true for both calls); M guarded.
template<int BM,int BN,int BK,int TM,int TN>
__global__ __launch_bounds__(256) void gemm_f32(const float* __restrict__ A,
    const float* __restrict__ B, float* __restrict__ C, int M, int N, int K){
  __shared__ float As[BK][BM+1];
  __shared__ float Bs[BK][BN+1];
  const int tid = threadIdx.x;
  const int tx = tid % (BN/TN);
  const int ty = tid / (BN/TN);
  const int row0 = blockIdx.x*BM, col0 = blockIdx.y*BN;
  float acc[TM][TN];
  #pragma unroll
  for (int i=0;i<TM;i++)
    #pragma unroll
    for(int j=0;j<TN;j++) acc[i][j]=0.f;

  for (int k0=0;k0<K;k0+=BK){
    for (int idx=tid; idx<BM*BK; idx+=256){
      int m=idx/BK, k=idx%BK; int gr=row0+m;
      As[k][m] = (gr<M)? A[(size_t)gr*K + k0 + k] : 0.f;
    }
    for (int idx=tid; idx<BK*BN; idx+=256){
      int k=idx/BN, n=idx%BN;
      Bs[k][n] = B[(size_t)(k0+k)*N + col0 + n];
    }
    __syncthreads();
    #pragma unroll
    for (int k=0;k<BK;k++){
      float a[TM], b[TN];
      #pragma unroll
      for (int i=0;i<TM;i++) a[i]=As[k][ty*TM+i];
      #pragma unroll
      for (int j=0;j<TN;j++) b[j]=Bs[k][tx*TN+j];
      #pragma unroll
      for (int i=0;i<TM;i++)
        #pragma unroll
        for (int j=0;j<TN;j++) acc[i][j] += a[i]*b[j];
    }
    __syncthreads();
  }
  #pragma unroll
  for (int i=0;i<TM;i++){
    int gr = row0 + ty*TM + i;
    if (gr < M){
      #pragma unroll
      for (int j=0;j<TN;j++) C[(size_t)gr*N + col0 + tx*TN + j] = acc[i][j];
    }
  }
}

// ---------- per-node attention halves, conv1: a[n,h] = dot(h1[n,h,:], att[h,:]) ----------
__global__ void a1_kernel(const float* __restrict__ h1, const float* __restrict__ att_src,
                          const float* __restrict__ att_dst,
                          float* __restrict__ a_src, float* __restrict__ a_dst){
  int i = blockIdx.x*blockDim.x + threadIdx.x;
  if (i >= N_NODES*H1) return;
  int n = i / H1, h = i % H1;
  const float* hp = h1 + (size_t)n*C1 + h*D1;
  float s=0.f, d=0.f;
  #pragma unroll
  for (int k=0;k<D1;k++){ float v = hp[k]; s += v*att_src[h*D1+k]; d += v*att_dst[h*D1+k]; }
  a_src[i]=s; a_dst[i]=d;
}

// ---------- per-node attention halves, conv2 (1 head, 64 feats) ----------
__global__ void a2_kernel(const float* __restrict__ h2, const float* __restrict__ att_src,
                          const float* __restrict__ att_dst,
                          float* __restrict__ a_src, float* __restrict__ a_dst){
  int n = blockIdx.x*blockDim.x + threadIdx.x;
  if (n >= N_NODES) return;
  const float* hp = h2 + (size_t)n*C2;
  float s=0.f, d=0.f;
  #pragma unroll
  for (int k=0;k<C2;k++){ float v = hp[k]; s += v*att_src[k]; d += v*att_dst[k]; }
  a_src[n]=s; a_dst[n]=d;
}

// ---------- edge pass 1 (conv1): atomic max of logits per (dst, head) + degree count ----------
__global__ void edge_max1(const int* __restrict__ ei, const float* __restrict__ a_src,
                          const float* __restrict__ a_dst, unsigned* __restrict__ mkey,
                          int* __restrict__ counts){
  int e = blockIdx.x*blockDim.x + threadIdx.x;
  if (e >= ETOT) return;
  int s, d;
  if (e < N_EDGES){ s = ei[e]; d = ei[N_EDGES + e]; } else { s = d = e - N_EDGES; }
  atomicAdd(&counts[d], 1);
  #pragma unroll
  for (int h=0; h<H1; ++h){
    float l = lrelu(a_src[s*H1+h] + a_dst[d*H1+h]);
    atomicMax(&mkey[d*H1+h], fkey(l));
  }
}

// ---------- decode mkey -> float in place ----------
__global__ void decode_kernel(unsigned* __restrict__ m, int n){
  int i = blockIdx.x*blockDim.x + threadIdx.x;
  if (i < n){ unsigned u = m[i]; ((float*)m)[i] = funkey(u); }
}

// ---------- edge pass 2 (conv1): atomic sum of exp(l - m) per (dst, head) ----------
__global__ void edge_sum1(const int* __restrict__ ei, const float* __restrict__ a_src,
                          const float* __restrict__ a_dst, const float* __restrict__ m,
                          float* __restrict__ ssum){
  int e = blockIdx.x*blockDim.x + threadIdx.x;
  if (e >= ETOT) return;
  int s, d;
  if (e < N_EDGES){ s = ei[e]; d = ei[N_EDGES + e]; } else { s = d = e - N_EDGES; }
  #pragma unroll
  for (int h=0; h<H1; ++h){
    float l = lrelu(a_src[s*H1+h] + a_dst[d*H1+h]);
    atomicAdd(&ssum[d*H1+h], __expf(l - m[d*H1+h]));
  }
}

// ---------- edge passes, conv2 (single head) ----------
__global__ void edge_max2(const int* __restrict__ ei, const float* __restrict__ a_src,
                          const float* __restrict__ a_dst, unsigned* __restrict__ mkey){
  int e = blockIdx.x*blockDim.x + threadIdx.x;
  if (e >= ETOT) return;
  int s, d;
  if (e < N_EDGES){ s = ei[e]; d = ei[N_EDGES + e]; } else { s = d = e - N_EDGES; }
  float l = lrelu(a_src[s] + a_dst[d]);
  atomicMax(&mkey[d], fkey(l));
}
__global__ void edge_sum2(const int* __restrict__ ei, const float* __restrict__ a_src,
                          const float* __restrict__ a_dst, const float* __restrict__ m,
                          float* __restrict__ ssum){
  int e = blockIdx.x*blockDim.x + threadIdx.x;
  if (e >= ETOT) return;
  int s, d;
  if (e < N_EDGES){ s = ei[e]; d = ei[N_EDGES + e]; } else { s = d = e - N_EDGES; }
  float l = lrelu(a_src[s] + a_dst[d]);
  atomicAdd(&ssum[d], __expf(l - m[d]));
}

// ---------- exclusive scan of counts -> rowptr (single block) ----------
__global__ __launch_bounds__(1024) void scan_kernel(const int* __restrict__ counts,
    int* __restrict__ rowptr, int* __restrict__ cursor, int n){
  __shared__ int sdata[1024];
  __shared__ int carry;
  if (threadIdx.x == 0) carry = 0;
  __syncthreads();
  for (int base=0; base<n; base+=1024){
    int i = base + (int)threadIdx.x;
    int v = (i<n)? counts[i] : 0;
    sdata[threadIdx.x] = v;
    __syncthreads();
    for (int off=1; off<1024; off<<=1){
      int t = (threadIdx.x >= off)? sdata[threadIdx.x-off] : 0;
      __syncthreads();
      sdata[threadIdx.x] += t;
      __syncthreads();
    }
    int excl = sdata[threadIdx.x] - v;
    if (i < n){ int r = carry + excl; rowptr[i] = r; cursor[i] = r; }
    __syncthreads();
    if (threadIdx.x == 0) carry += sdata[1023];
    __syncthreads();
  }
  if (threadIdx.x == 0) rowptr[n] = carry;
}

// ---------- scatter edges into CSR slots ----------
__global__ void scatter_kernel(const int* __restrict__ ei, int* __restrict__ cursor,
                               int* __restrict__ csr_src){
  int e = blockIdx.x*blockDim.x + threadIdx.x;
  if (e >= ETOT) return;
  int s, d;
  if (e < N_EDGES){ s = ei[e]; d = ei[N_EDGES + e]; } else { s = d = e - N_EDGES; }
  int slot = atomicAdd(&cursor[d], 1);
  csr_src[slot] = s;
}

// ---------- conv1 aggregation: one block per dst, 384 threads (one per (h,d)) ----------
__global__ __launch_bounds__(C1) void agg1_kernel(const int* __restrict__ rowptr,
    const int* __restrict__ csr_src, const float* __restrict__ h1,
    const float* __restrict__ a_src, const float* __restrict__ a_dst,
    const float* __restrict__ m, const float* __restrict__ ssum,
    const float* __restrict__ bias, float* __restrict__ out1){
  int d = blockIdx.x;
  int tid = threadIdx.x;           // 0..383
  int head = tid >> 5;             // D1 = 32
  float adst = a_dst[d*H1+head];
  float mm   = m[d*H1+head];
  float invs = 1.0f / ssum[d*H1+head];
  int r0 = rowptr[d], r1 = rowptr[d+1];
  float acc = 0.f;
  for (int j=r0; j<r1; ++j){
    int s = csr_src[j];
    float l = lrelu(a_src[s*H1+head] + adst);
    float alpha = __expf(l - mm) * invs;
    acc += alpha * h1[(size_t)s*C1 + tid];
  }
  out1[(size_t)d*C1 + tid] = fmaxf(acc + bias[tid], 0.f);   // + bias, ReLU fused
}

// ---------- conv2 aggregation: one block per dst, 64 threads ----------
__global__ __launch_bounds__(C2) void agg2_kernel(const int* __restrict__ rowptr,
    const int* __restrict__ csr_src, const float* __restrict__ h2,
    const float* __restrict__ a_src, const float* __restrict__ a_dst,
    const float* __restrict__ m, const float* __restrict__ ssum,
    const float* __restrict__ bias, float* __restrict__ out2){
  int d = blockIdx.x;
  int tid = threadIdx.x;           // 0..63
  float adst = a_dst[d];
  float mm   = m[d];
  float invs = 1.0f / ssum[d];
  int r0 = rowptr[d], r1 = rowptr[d+1];
  float acc = 0.f;
  for (int j=r0; j<r1; ++j){
    int s = csr_src[j];
    float l = lrelu(a_src[s] + adst);
    float alpha = __expf(l - mm) * invs;
    acc += alpha * h2[(size_t)s*C2 + tid];
  }
  out2[(size_t)d*C2 + tid] = acc + bias[tid];   // no ReLU on conv2
}

// ---------- mean pool ----------
__global__ void pool_kernel(const float* __restrict__ out2, const int* __restrict__ batch,
                            float* __restrict__ sums, int* __restrict__ cnt){
  int i = blockIdx.x*blockDim.x + threadIdx.x;
  if (i >= N_NODES*C2) return;
  int n = i >> 6, f = i & 63;
  int g = batch[n];
  atomicAdd(&sums[g*C2 + f], out2[i]);
  if (f == 0) atomicAdd(&cnt[g], 1);
}
__global__ void finalize_kernel(const float* __restrict__ sums, const int* __restrict__ cnt,
                                float* __restrict__ out){
  int i = blockIdx.x*blockDim.x + threadIdx.x;
  if (i >= G_GRAPHS*C2) return;
  int g = i >> 6;
  out[i] = sums[i] / fmaxf((float)cnt[g], 1.f);
}

// ---------- launch ----------
extern "C" void kernel_launch(void* const* d_in, const int* in_sizes, int n_in,
                              void* d_out, int out_size, void* d_ws, size_t ws_size,
                              hipStream_t stream) {
  const float* x        = (const float*)d_in[0];
  const int*   ei       = (const int*)  d_in[1];
  const int*   batch    = (const int*)  d_in[2];
  const float* W1       = (const float*)d_in[3];
  const float* att_src1 = (const float*)d_in[4];
  const float* att_dst1 = (const float*)d_in[5];
  const float* bias1    = (const float*)d_in[6];
  const float* W2       = (const float*)d_in[7];
  const float* att_src2 = (const float*)d_in[8];
  const float* att_dst2 = (const float*)d_in[9];
  const float* bias2    = (const float*)d_in[10];
  float* out = (float*)d_out;

  char* ws = (char*)d_ws;
  size_t o = 0;
  auto alloc = [&](size_t bytes)->size_t{ size_t r=o; o=(o+bytes+255)&~(size_t)255; return r; };

  size_t h1_o     = alloc((size_t)N_NODES*C1*4);   // 76.8 MB
  size_t out1_o   = alloc((size_t)N_NODES*C1*4);   // 76.8 MB
  size_t asrc1_o  = alloc((size_t)N_NODES*H1*4);
  size_t adst1_o  = alloc((size_t)N_NODES*H1*4);
  size_t zero_beg = o;
  size_t mkey1_o  = alloc((size_t)N_NODES*H1*4);
  size_t s1_o     = alloc((size_t)N_NODES*H1*4);
  size_t counts_o = alloc((size_t)N_NODES*4);
  size_t mkey2_o  = alloc((size_t)N_NODES*4);
  size_t s2_o     = alloc((size_t)N_NODES*4);
  size_t pool_o   = alloc((size_t)G_GRAPHS*C2*4);
  size_t cnt_o    = alloc((size_t)G_GRAPHS*4);
  size_t zero_end = o;
  size_t rowptr_o = alloc((size_t)(N_NODES+1)*4);
  size_t cursor_o = alloc((size_t)N_NODES*4);
  size_t csr_o    = alloc((size_t)ETOT*4);
  size_t asrc2_o  = alloc((size_t)N_NODES*4);
  size_t adst2_o  = alloc((size_t)N_NODES*4);
  // conv2 node buffers alias h1's region (h1 dead after agg1)
  size_t h2_o   = h1_o;
  size_t out2_o = h1_o + (size_t)N_NODES*C2*4;

  float*    h1f    = (float*)   (ws + h1_o);
  float*    out1f  = (float*)   (ws + out1_o);
  float*    asrc1  = (float*)   (ws + asrc1_o);
  float*    adst1  = (float*)   (ws + adst1_o);
  unsigned* mkey1  = (unsigned*)(ws + mkey1_o);
  float*    s1f    = (float*)   (ws + s1_o);
  int*      counts = (int*)     (ws + counts_o);
  unsigned* mkey2  = (unsigned*)(ws + mkey2_o);
  float*    s2f    = (float*)   (ws + s2_o);
  float*    poolf  = (float*)   (ws + pool_o);
  int*      cnt    = (int*)     (ws + cnt_o);
  int*      rowptr = (int*)     (ws + rowptr_o);
  int*      cursor = (int*)     (ws + cursor_o);
  int*      csrsrc = (int*)     (ws + csr_o);
  float*    asrc2  = (float*)   (ws + asrc2_o);
  float*    adst2  = (float*)   (ws + adst2_o);
  float*    h2f    = (float*)   (ws + h2_o);
  float*    out2f  = (float*)   (ws + out2_o);

  hipMemsetAsync(ws + zero_beg, 0, zero_end - zero_beg, stream);

  const int TPB = 256;
  int egrid = (ETOT + TPB - 1)/TPB;

  // conv1
  gemm_f32<64,64,32,4,4><<<dim3((N_NODES+63)/64, C1/64), 256, 0, stream>>>(x, W1, h1f, N_NODES, C1, F_IN);
  a1_kernel<<<(N_NODES*H1 + TPB-1)/TPB, TPB, 0, stream>>>(h1f, att_src1, att_dst1, asrc1, adst1);
  edge_max1<<<egrid, TPB, 0, stream>>>(ei, asrc1, adst1, mkey1, counts);
  scan_kernel<<<1, 1024, 0, stream>>>(counts, rowptr, cursor, N_NODES);
  scatter_kernel<<<egrid, TPB, 0, stream>>>(ei, cursor, csrsrc);
  decode_kernel<<<(N_NODES*H1 + TPB-1)/TPB, TPB, 0, stream>>>(mkey1, N_NODES*H1);
  edge_sum1<<<egrid, TPB, 0, stream>>>(ei, asrc1, adst1, (const float*)mkey1, s1f);
  agg1_kernel<<<N_NODES, C1, 0, stream>>>(rowptr, csrsrc, h1f, asrc1, adst1,
                                          (const float*)mkey1, s1f, bias1, out1f);
  // conv2
  gemm_f32<64,64,32,4,4><<<dim3((N_NODES+63)/64, C2/64), 256, 0, stream>>>(out1f, W2, h2f, N_NODES, C2, C1);
  a2_kernel<<<(N_NODES + TPB-1)/TPB, TPB, 0, stream>>>(h2f, att_src2, att_dst2, asrc2, adst2);
  edge_max2<<<egrid, TPB, 0, stream>>>(ei, asrc2, adst2, mkey2);
  decode_kernel<<<(N_NODES + TPB-1)/TPB, TPB, 0, stream>>>(mkey2, N_NODES);
  edge_sum2<<<egrid, TPB, 0, stream>>>(ei, asrc2, adst2, (const float*)mkey2, s2f);
  agg2_kernel<<<N_NODES, C2, 0, stream>>>(rowptr, csrsrc, h2f, asrc2, adst2,
                                          (const float*)mkey2, s2f, bias2, out2f);
  // pool
  pool_kernel<<<(N_NODES*C2 + TPB-1)/TPB, TPB, 0, stream>>>(out2f, batch, poolf, cnt);
  finalize_kernel<<<(G_GRAPHS*C2 + TPB-1)/TPB, TPB, 0, stream>>>(poolf, cnt, out);
}

// Round 2
// 918.620 us; speedup vs baseline: 2.1817x; 2.1817x over previous
//
#include <hip/hip_runtime.h>

#define N_NODES 50000
#define N_EDGES 800000
#define ETOT (N_EDGES + N_NODES)   // edges + self loops = 850000
#define G_GRAPHS 256
#define F_IN 128
#define H1 12
#define D1 32
#define C1 (H1*D1)   // 384
#define C2 64
#define NEG 0.2f
#define SCAN_B 1024
#define NBLK_SCAN ((N_NODES + SCAN_B - 1)/SCAN_B)   // 49

__device__ __forceinline__ float lrelu(float x){ return x > 0.f ? x : NEG*x; }

// ---------- fp32 tiled GEMM: C[M,N] = A[M,K] @ B[K,N] ----------
template<int BM,int BN,int BK,int TM,int TN>
__global__ __launch_bounds__(256) void gemm_f32(const float* __restrict__ A,
    const float* __restrict__ B, float* __restrict__ C, int M, int N, int K){
  __shared__ float As[BK][BM+1];
  __shared__ float Bs[BK][BN+1];
  const int tid = threadIdx.x;
  const int tx = tid % (BN/TN);
  const int ty = tid / (BN/TN);
  const int row0 = blockIdx.x*BM, col0 = blockIdx.y*BN;
  float acc[TM][TN];
  #pragma unroll
  for (int i=0;i<TM;i++)
    #pragma unroll
    for(int j=0;j<TN;j++) acc[i][j]=0.f;

  for (int k0=0;k0<K;k0+=BK){
    for (int idx=tid; idx<BM*BK; idx+=256){
      int m=idx/BK, k=idx%BK; int gr=row0+m;
      As[k][m] = (gr<M)? A[(size_t)gr*K + k0 + k] : 0.f;
    }
    for (int idx=tid; idx<BK*BN; idx+=256){
      int k=idx/BN, n=idx%BN;
      Bs[k][n] = B[(size_t)(k0+k)*N + col0 + n];
    }
    __syncthreads();
    #pragma unroll
    for (int k=0;k<BK;k++){
      float a[TM], b[TN];
      #pragma unroll
      for (int i=0;i<TM;i++) a[i]=As[k][ty*TM+i];
      #pragma unroll
      for (int j=0;j<TN;j++) b[j]=Bs[k][tx*TN+j];
      #pragma unroll
      for (int i=0;i<TM;i++)
        #pragma unroll
        for (int j=0;j<TN;j++) acc[i][j] += a[i]*b[j];
    }
    __syncthreads();
  }
  #pragma unroll
  for (int i=0;i<TM;i++){
    int gr = row0 + ty*TM + i;
    if (gr < M){
      #pragma unroll
      for (int j=0;j<TN;j++) C[(size_t)gr*N + col0 + tx*TN + j] = acc[i][j];
    }
  }
}

// ---------- per-node attention halves, conv1 ----------
__global__ void a1_kernel(const float* __restrict__ h1, const float* __restrict__ att_src,
                          const float* __restrict__ att_dst,
                          float* __restrict__ a_src, float* __restrict__ a_dst){
  int i = blockIdx.x*blockDim.x + threadIdx.x;
  if (i >= N_NODES*H1) return;
  int n = i / H1, h = i % H1;
  const float* hp = h1 + (size_t)n*C1 + h*D1;
  float s=0.f, d=0.f;
  #pragma unroll
  for (int k=0;k<D1;k++){ float v = hp[k]; s += v*att_src[h*D1+k]; d += v*att_dst[h*D1+k]; }
  a_src[i]=s; a_dst[i]=d;
}

// ---------- per-node attention halves, conv2 ----------
__global__ void a2_kernel(const float* __restrict__ h2, const float* __restrict__ att_src,
                          const float* __restrict__ att_dst,
                          float* __restrict__ a_src, float* __restrict__ a_dst){
  int n = blockIdx.x*blockDim.x + threadIdx.x;
  if (n >= N_NODES) return;
  const float* hp = h2 + (size_t)n*C2;
  float s=0.f, d=0.f;
  #pragma unroll
  for (int k=0;k<C2;k++){ float v = hp[k]; s += v*att_src[k]; d += v*att_dst[k]; }
  a_src[n]=s; a_dst[n]=d;
}

// ---------- degree count ----------
__global__ void count_kernel(const int* __restrict__ ei, int* __restrict__ counts){
  int e = blockIdx.x*blockDim.x + threadIdx.x;
  if (e >= ETOT) return;
  int d = (e < N_EDGES) ? ei[N_EDGES + e] : (e - N_EDGES);
  atomicAdd(&counts[d], 1);
}

// ---------- hierarchical exclusive scan ----------
__global__ __launch_bounds__(SCAN_B) void scan_pass1(const int* __restrict__ counts,
    int* __restrict__ excl, int* __restrict__ bsum){
  __shared__ int sdata[SCAN_B];
  int i = blockIdx.x*SCAN_B + threadIdx.x;
  int v = (i < N_NODES) ? counts[i] : 0;
  sdata[threadIdx.x] = v;
  __syncthreads();
  for (int off=1; off<SCAN_B; off<<=1){
    int t = (threadIdx.x >= off) ? sdata[threadIdx.x-off] : 0;
    __syncthreads();
    sdata[threadIdx.x] += t;
    __syncthreads();
  }
  if (i < N_NODES) excl[i] = sdata[threadIdx.x] - v;
  if (threadIdx.x == SCAN_B-1) bsum[blockIdx.x] = sdata[SCAN_B-1];
}
__global__ void scan_pass2(int* __restrict__ bsum){
  if (threadIdx.x == 0){
    int acc = 0;
    for (int b=0;b<NBLK_SCAN;b++){ int t = bsum[b]; bsum[b] = acc; acc += t; }
  }
}
__global__ void scan_pass3(int* __restrict__ rowptr, const int* __restrict__ bsum,
                           int* __restrict__ cursor){
  int i = blockIdx.x*blockDim.x + threadIdx.x;
  if (i < N_NODES){
    int r = rowptr[i] + bsum[i/SCAN_B];
    rowptr[i] = r; cursor[i] = r;
  }
  if (i == N_NODES) rowptr[N_NODES] = ETOT;
}

// ---------- scatter edges into CSR slots ----------
__global__ void scatter_kernel(const int* __restrict__ ei, int* __restrict__ cursor,
                               int* __restrict__ csr_src){
  int e = blockIdx.x*blockDim.x + threadIdx.x;
  if (e >= ETOT) return;
  int s, d;
  if (e < N_EDGES){ s = ei[e]; d = ei[N_EDGES + e]; } else { s = d = e - N_EDGES; }
  int slot = atomicAdd(&cursor[d], 1);
  csr_src[slot] = s;
}

// ---------- conv1 fused softmax+aggregate: one block per dst, 384 threads ----------
__global__ __launch_bounds__(C1) void agg1_fused(const int* __restrict__ rowptr,
    const int* __restrict__ csr_src, const float* __restrict__ h1,
    const float* __restrict__ a_src, const float* __restrict__ a_dst,
    const float* __restrict__ bias, float* __restrict__ out1){
  int d = blockIdx.x;
  int tid = threadIdx.x;           // 0..383
  int head = tid >> 5;             // 0..11
  int lane5 = tid & 31;            // 0..31
  __shared__ float sh_max[H1];
  int r0 = rowptr[d], r1 = rowptr[d+1];
  float adst = a_dst[d*H1 + head];

  // phase 1: per-head max over incoming edges
  float mx = -__builtin_inff();
  for (int j = r0 + lane5; j < r1; j += 32){
    int s = csr_src[j];
    mx = fmaxf(mx, lrelu(a_src[s*H1 + head] + adst));
  }
  #pragma unroll
  for (int off=16; off; off>>=1) mx = fmaxf(mx, __shfl_xor(mx, off, 32));
  if (lane5 == 0) sh_max[head] = mx;
  __syncthreads();
  float mm = sh_max[head];

  // phase 2: fused sum + weighted aggregation (unnormalized), divide at end
  float acc = 0.f, ssum = 0.f;
  for (int j = r0; j < r1; ++j){
    int s = csr_src[j];
    float l = lrelu(a_src[s*H1 + head] + adst);
    float w = __expf(l - mm);
    ssum += w;
    acc  += w * h1[(size_t)s*C1 + tid];
  }
  out1[(size_t)d*C1 + tid] = fmaxf(acc/ssum + bias[tid], 0.f);   // + bias, ReLU fused
}

// ---------- conv2 fused softmax+aggregate: one block (=1 wave) per dst, 64 threads ----------
__global__ __launch_bounds__(C2) void agg2_fused(const int* __restrict__ rowptr,
    const int* __restrict__ csr_src, const float* __restrict__ h2,
    const float* __restrict__ a_src, const float* __restrict__ a_dst,
    const float* __restrict__ bias, float* __restrict__ out2){
  int d = blockIdx.x;
  int tid = threadIdx.x;           // 0..63
  int r0 = rowptr[d], r1 = rowptr[d+1];
  float adst = a_dst[d];

  // phase 1: max over incoming edges (64-lane strided + wave reduce)
  float mx = -__builtin_inff();
  for (int j = r0 + tid; j < r1; j += 64){
    int s = csr_src[j];
    mx = fmaxf(mx, lrelu(a_src[s] + adst));
  }
  #pragma unroll
  for (int off=32; off; off>>=1) mx = fmaxf(mx, __shfl_xor(mx, off, 64));

  // phase 2: fused sum + aggregation
  float acc = 0.f, ssum = 0.f;
  for (int j = r0; j < r1; ++j){
    int s = csr_src[j];
    float l = lrelu(a_src[s] + adst);
    float w = __expf(l - mx);
    ssum += w;
    acc  += w * h2[(size_t)s*C2 + tid];
  }
  out2[(size_t)d*C2 + tid] = acc/ssum + bias[tid];
}

// ---------- mean pool ----------
__global__ void pool_kernel(const float* __restrict__ out2, const int* __restrict__ batch,
                            float* __restrict__ sums, int* __restrict__ cnt){
  int i = blockIdx.x*blockDim.x + threadIdx.x;
  if (i >= N_NODES*C2) return;
  int n = i >> 6, f = i & 63;
  int g = batch[n];
  atomicAdd(&sums[g*C2 + f], out2[i]);
  if (f == 0) atomicAdd(&cnt[g], 1);
}
__global__ void finalize_kernel(const float* __restrict__ sums, const int* __restrict__ cnt,
                                float* __restrict__ out){
  int i = blockIdx.x*blockDim.x + threadIdx.x;
  if (i >= G_GRAPHS*C2) return;
  int g = i >> 6;
  out[i] = sums[i] / fmaxf((float)cnt[g], 1.f);
}

// ---------- launch ----------
extern "C" void kernel_launch(void* const* d_in, const int* in_sizes, int n_in,
                              void* d_out, int out_size, void* d_ws, size_t ws_size,
                              hipStream_t stream) {
  const float* x        = (const float*)d_in[0];
  const int*   ei       = (const int*)  d_in[1];
  const int*   batch    = (const int*)  d_in[2];
  const float* W1       = (const float*)d_in[3];
  const float* att_src1 = (const float*)d_in[4];
  const float* att_dst1 = (const float*)d_in[5];
  const float* bias1    = (const float*)d_in[6];
  const float* W2       = (const float*)d_in[7];
  const float* att_src2 = (const float*)d_in[8];
  const float* att_dst2 = (const float*)d_in[9];
  const float* bias2    = (const float*)d_in[10];
  float* out = (float*)d_out;

  char* ws = (char*)d_ws;
  size_t o = 0;
  auto alloc = [&](size_t bytes)->size_t{ size_t r=o; o=(o+bytes+255)&~(size_t)255; return r; };

  size_t h1_o     = alloc((size_t)N_NODES*C1*4);   // 76.8 MB (aliased for h2/out2 later)
  size_t out1_o   = alloc((size_t)N_NODES*C1*4);   // 76.8 MB
  size_t asrc1_o  = alloc((size_t)N_NODES*H1*4);
  size_t adst1_o  = alloc((size_t)N_NODES*H1*4);
  size_t zero_beg = o;
  size_t counts_o = alloc((size_t)N_NODES*4);
  size_t pool_o   = alloc((size_t)G_GRAPHS*C2*4);
  size_t cnt_o    = alloc((size_t)G_GRAPHS*4);
  size_t zero_end = o;
  size_t rowptr_o = alloc((size_t)(N_NODES+1)*4);
  size_t bsum_o   = alloc((size_t)NBLK_SCAN*4);
  size_t cursor_o = alloc((size_t)N_NODES*4);
  size_t csr_o    = alloc((size_t)ETOT*4);
  size_t asrc2_o  = alloc((size_t)N_NODES*4);
  size_t adst2_o  = alloc((size_t)N_NODES*4);
  size_t h2_o   = h1_o;                                   // alias: h1 dead after agg1
  size_t out2_o = h1_o + (size_t)N_NODES*C2*4;

  float* h1f    = (float*)(ws + h1_o);
  float* out1f  = (float*)(ws + out1_o);
  float* asrc1  = (float*)(ws + asrc1_o);
  float* adst1  = (float*)(ws + adst1_o);
  int*   counts = (int*)  (ws + counts_o);
  float* poolf  = (float*)(ws + pool_o);
  int*   cnt    = (int*)  (ws + cnt_o);
  int*   rowptr = (int*)  (ws + rowptr_o);
  int*   bsum   = (int*)  (ws + bsum_o);
  int*   cursor = (int*)  (ws + cursor_o);
  int*   csrsrc = (int*)  (ws + csr_o);
  float* asrc2  = (float*)(ws + asrc2_o);
  float* adst2  = (float*)(ws + adst2_o);
  float* h2f    = (float*)(ws + h2_o);
  float* out2f  = (float*)(ws + out2_o);

  hipMemsetAsync(ws + zero_beg, 0, zero_end - zero_beg, stream);

  const int TPB = 256;
  int egrid = (ETOT + TPB - 1)/TPB;

  // CSR build (independent of GEMM)
  count_kernel<<<egrid, TPB, 0, stream>>>(ei, counts);
  scan_pass1<<<NBLK_SCAN, SCAN_B, 0, stream>>>(counts, rowptr, bsum);
  scan_pass2<<<1, 64, 0, stream>>>(bsum);
  scan_pass3<<<(N_NODES + TPB)/TPB, TPB, 0, stream>>>(rowptr, bsum, cursor);
  scatter_kernel<<<egrid, TPB, 0, stream>>>(ei, cursor, csrsrc);

  // conv1
  gemm_f32<64,64,32,4,4><<<dim3((N_NODES+63)/64, C1/64), 256, 0, stream>>>(x, W1, h1f, N_NODES, C1, F_IN);
  a1_kernel<<<(N_NODES*H1 + TPB-1)/TPB, TPB, 0, stream>>>(h1f, att_src1, att_dst1, asrc1, adst1);
  agg1_fused<<<N_NODES, C1, 0, stream>>>(rowptr, csrsrc, h1f, asrc1, adst1, bias1, out1f);

  // conv2
  gemm_f32<64,64,32,4,4><<<dim3((N_NODES+63)/64, C2/64), 256, 0, stream>>>(out1f, W2, h2f, N_NODES, C2, C1);
  a2_kernel<<<(N_NODES + TPB-1)/TPB, TPB, 0, stream>>>(h2f, att_src2, att_dst2, asrc2, adst2);
  agg2_fused<<<N_NODES, C2, 0, stream>>>(rowptr, csrsrc, h2f, asrc2, adst2, bias2, out2f);

  // pool
  pool_kernel<<<(N_NODES*C2 + TPB-1)/TPB, TPB, 0, stream>>>(out2f, batch, poolf, cnt);
  finalize_kernel<<<(G_GRAPHS*C2 + TPB-1)/TPB, TPB, 0, stream>>>(poolf, cnt, out);
}

// Round 3
// 640.291 us; speedup vs baseline: 3.1300x; 1.4347x over previous
//
#include <hip/hip_runtime.h>

#define N_NODES 50000
#define N_EDGES 800000
#define ETOT (N_EDGES + N_NODES)   // 850000
#define G_GRAPHS 256
#define F_IN 128
#define H1 12
#define D1 32
#define C1 (H1*D1)   // 384
#define C2 64
#define NEG 0.2f
#define SCAN_B 1024
#define NBLK_SCAN ((N_NODES + SCAN_B - 1)/SCAN_B)   // 49

using bf16x8 = __attribute__((ext_vector_type(8))) short;
using f32x4  = __attribute__((ext_vector_type(4))) float;

__device__ __forceinline__ float lrelu(float x){ return x > 0.f ? x : NEG*x; }
__device__ __forceinline__ unsigned short f2bf(float f){
  unsigned u = __float_as_uint(f);
  u += 0x7fffu + ((u >> 16) & 1u);
  return (unsigned short)(u >> 16);
}
__device__ __forceinline__ float bf2f(unsigned short h){
  return __uint_as_float(((unsigned)h) << 16);
}

// ---------- cast / transpose prep ----------
__global__ void cast_x_kernel(const float* __restrict__ x, unsigned short* __restrict__ xb){
  int i = blockIdx.x*blockDim.x + threadIdx.x;   // handles 4 elems
  int base = i*4;
  if (base >= N_NODES*F_IN) return;
  float4 v = *(const float4*)(x + base);
  ushort4 o; o.x=f2bf(v.x); o.y=f2bf(v.y); o.z=f2bf(v.z); o.w=f2bf(v.w);
  *(ushort4*)(xb + base) = o;
}
// W[K][Nc] fp32 -> Wt[Nc][K] bf16
__global__ void transpose_w_kernel(const float* __restrict__ W, unsigned short* __restrict__ Wt,
                                   int K, int Nc){
  int i = blockIdx.x*blockDim.x + threadIdx.x;
  if (i >= K*Nc) return;
  int n = i / K, k = i % K;
  Wt[i] = f2bf(W[(size_t)k*Nc + n]);
}

// ---------- bf16 MFMA GEMM: C[M][N](bf16) = A[M][K](bf16) @ Bt[N][K](bf16)^T ----------
template<int BM,int BN,int WM,int WN>
__global__ __launch_bounds__(256) void gemm_mfma(const unsigned short* __restrict__ A,
    const unsigned short* __restrict__ Bt, unsigned short* __restrict__ C,
    int M, int N, int K){
  constexpr int BK = 32;
  __shared__ unsigned short As2[4][BM][8];   // [koct][row][8 k-elems] (16B units)
  __shared__ unsigned short Bs2[4][BN][8];
  const int tid  = threadIdx.x;
  const int wid  = tid >> 6, lane = tid & 63;
  constexpr int NWX = BN / WN;               // waves along N
  const int wrow = (wid / NWX) * WM, wcol = (wid % NWX) * WN;
  constexpr int MR = WM/16, NR = WN/16;
  const int row0 = blockIdx.x * BM, col0 = blockIdx.y * BN;
  const int r = lane & 15, koct = lane >> 4;
  f32x4 acc[MR][NR];
  #pragma unroll
  for (int m=0;m<MR;m++)
    #pragma unroll
    for (int n=0;n<NR;n++) acc[m][n] = f32x4{0.f,0.f,0.f,0.f};

  for (int k0 = 0; k0 < K; k0 += BK){
    for (int s = tid; s < BM*8; s += 256){          // BM*32 elems as ushort4
      int rr = s >> 3, cc = (s & 7) * 4;
      int gr = row0 + rr;
      ushort4 v = (gr < M) ? *(const ushort4*)(A + (size_t)gr*K + k0 + cc)
                           : ushort4{0,0,0,0};
      *(ushort4*)(&As2[cc>>3][rr][cc&7]) = v;
    }
    for (int s = tid; s < BN*8; s += 256){
      int rr = s >> 3, cc = (s & 7) * 4;
      ushort4 v = *(const ushort4*)(Bt + (size_t)(col0+rr)*K + k0 + cc);
      *(ushort4*)(&Bs2[cc>>3][rr][cc&7]) = v;
    }
    __syncthreads();
    bf16x8 af[MR], bq[NR];
    #pragma unroll
    for (int m=0;m<MR;m++) af[m] = *(const bf16x8*)(&As2[koct][wrow + m*16 + r][0]);
    #pragma unroll
    for (int n=0;n<NR;n++) bq[n] = *(const bf16x8*)(&Bs2[koct][wcol + n*16 + r][0]);
    #pragma unroll
    for (int m=0;m<MR;m++)
      #pragma unroll
      for (int n=0;n<NR;n++)
        acc[m][n] = __builtin_amdgcn_mfma_f32_16x16x32_bf16(af[m], bq[n], acc[m][n], 0,0,0);
    __syncthreads();
  }
  #pragma unroll
  for (int m=0;m<MR;m++){
    #pragma unroll
    for (int rr=0; rr<4; rr++){
      int grow = row0 + wrow + m*16 + koct*4 + rr;
      if (grow < M){
        #pragma unroll
        for (int n=0;n<NR;n++)
          C[(size_t)grow*N + col0 + wcol + n*16 + r] = f2bf(acc[m][n][rr]);
      }
    }
  }
}

// ---------- per-node attention halves, conv1 (bf16 h1) ----------
__global__ void a1_kernel(const unsigned short* __restrict__ h1,
    const float* __restrict__ att_src, const float* __restrict__ att_dst,
    float* __restrict__ a_src, float* __restrict__ a_dst){
  int i = blockIdx.x*blockDim.x + threadIdx.x;
  if (i >= N_NODES*H1) return;
  int n = i / H1, h = i % H1;
  const unsigned short* hp = h1 + (size_t)n*C1 + h*D1;
  float s=0.f, d=0.f;
  #pragma unroll
  for (int k4=0;k4<8;k4++){
    ushort4 v = *(const ushort4*)(hp + k4*4);
    int b = h*D1 + k4*4;
    s += bf2f(v.x)*att_src[b] + bf2f(v.y)*att_src[b+1] + bf2f(v.z)*att_src[b+2] + bf2f(v.w)*att_src[b+3];
    d += bf2f(v.x)*att_dst[b] + bf2f(v.y)*att_dst[b+1] + bf2f(v.z)*att_dst[b+2] + bf2f(v.w)*att_dst[b+3];
  }
  a_src[i]=s; a_dst[i]=d;
}
__global__ void a2_kernel(const unsigned short* __restrict__ h2,
    const float* __restrict__ att_src, const float* __restrict__ att_dst,
    float* __restrict__ a_src, float* __restrict__ a_dst){
  int n = blockIdx.x*blockDim.x + threadIdx.x;
  if (n >= N_NODES) return;
  const unsigned short* hp = h2 + (size_t)n*C2;
  float s=0.f, d=0.f;
  #pragma unroll
  for (int k4=0;k4<16;k4++){
    ushort4 v = *(const ushort4*)(hp + k4*4);
    int b = k4*4;
    s += bf2f(v.x)*att_src[b] + bf2f(v.y)*att_src[b+1] + bf2f(v.z)*att_src[b+2] + bf2f(v.w)*att_src[b+3];
    d += bf2f(v.x)*att_dst[b] + bf2f(v.y)*att_dst[b+1] + bf2f(v.z)*att_dst[b+2] + bf2f(v.w)*att_dst[b+3];
  }
  a_src[n]=s; a_dst[n]=d;
}

// ---------- CSR build ----------
__global__ void count_kernel(const int* __restrict__ ei, int* __restrict__ counts){
  int e = blockIdx.x*blockDim.x + threadIdx.x;
  if (e >= ETOT) return;
  int d = (e < N_EDGES) ? ei[N_EDGES + e] : (e - N_EDGES);
  atomicAdd(&counts[d], 1);
}
__global__ __launch_bounds__(SCAN_B) void scan_pass1(const int* __restrict__ counts,
    int* __restrict__ excl, int* __restrict__ bsum){
  __shared__ int sdata[SCAN_B];
  int i = blockIdx.x*SCAN_B + threadIdx.x;
  int v = (i < N_NODES) ? counts[i] : 0;
  sdata[threadIdx.x] = v;
  __syncthreads();
  for (int off=1; off<SCAN_B; off<<=1){
    int t = (threadIdx.x >= off) ? sdata[threadIdx.x-off] : 0;
    __syncthreads();
    sdata[threadIdx.x] += t;
    __syncthreads();
  }
  if (i < N_NODES) excl[i] = sdata[threadIdx.x] - v;
  if (threadIdx.x == SCAN_B-1) bsum[blockIdx.x] = sdata[SCAN_B-1];
}
__global__ void scan_pass2(int* __restrict__ bsum){
  if (threadIdx.x == 0){
    int acc = 0;
    for (int b=0;b<NBLK_SCAN;b++){ int t = bsum[b]; bsum[b] = acc; acc += t; }
  }
}
__global__ void scan_pass3(int* __restrict__ rowptr, const int* __restrict__ bsum,
                           int* __restrict__ cursor){
  int i = blockIdx.x*blockDim.x + threadIdx.x;
  if (i < N_NODES){
    int r = rowptr[i] + bsum[i/SCAN_B];
    rowptr[i] = r; cursor[i] = r;
  }
  if (i == N_NODES) rowptr[N_NODES] = ETOT;
}
__global__ void scatter_kernel(const int* __restrict__ ei, int* __restrict__ cursor,
                               int* __restrict__ csr_src){
  int e = blockIdx.x*blockDim.x + threadIdx.x;
  if (e >= ETOT) return;
  int s, d;
  if (e < N_EDGES){ s = ei[e]; d = ei[N_EDGES + e]; } else { s = d = e - N_EDGES; }
  int slot = atomicAdd(&cursor[d], 1);
  csr_src[slot] = s;
}

// ---------- per-dst softmax -> normalized alpha (per-head planes [h][slot]) ----------
template<int H>
__global__ __launch_bounds__(64) void alpha_kernel(const int* __restrict__ rowptr,
    const int* __restrict__ csr, const float* __restrict__ asrc,
    const float* __restrict__ adst, float* __restrict__ alpha){
  int d = blockIdx.x;
  int lane = threadIdx.x;
  int r0 = rowptr[d], r1 = rowptr[d+1];
  for (int h = 0; h < H; ++h){
    float ad = adst[d*H + h];
    float m = -1e30f, ss = 0.f;
    for (int j = r0 + lane; j < r1; j += 64){
      int s = csr[j];
      float l = lrelu(asrc[s*H + h] + ad);
      float mn = fmaxf(m, l);
      ss = ss * __expf(m - mn) + __expf(l - mn);
      m = mn;
    }
    #pragma unroll
    for (int off = 32; off; off >>= 1){
      float m2 = __shfl_xor(m, off);
      float s2 = __shfl_xor(ss, off);
      float mn = fmaxf(m, m2);
      ss = ss * __expf(m - mn) + s2 * __expf(m2 - mn);
      m = mn;
    }
    float inv = 1.f / ss;
    for (int j = r0 + lane; j < r1; j += 64){
      int s = csr[j];
      float l = lrelu(asrc[s*H + h] + ad);
      alpha[(size_t)h*ETOT + j] = __expf(l - m) * inv;
    }
  }
}

// ---------- conv1 aggregation: 384 threads/dst, 4 edges concurrent, ushort4 gathers ----------
#define AGG1_CH 32
__global__ __launch_bounds__(384) void agg1_kernel(const int* __restrict__ rowptr,
    const int* __restrict__ csr, const unsigned short* __restrict__ h1,
    const float* __restrict__ alpha, const float* __restrict__ bias,
    unsigned short* __restrict__ out1){
  int d = blockIdx.x, tid = threadIdx.x;
  int r0 = rowptr[d], r1 = rowptr[d+1];
  __shared__ float w_lds[AGG1_CH*H1];
  __shared__ int   s_lds[AGG1_CH];
  __shared__ float red[3][C1];
  int grp = tid / 96;                 // 0..3: edge group
  int fb  = (tid % 96) * 4;           // features fb..fb+3 (same head)
  int hh  = fb >> 5;                  // head
  float a0=0.f, a1=0.f, a2=0.f, a3=0.f;
  for (int c0 = r0; c0 < r1; c0 += AGG1_CH){
    int nc = min(AGG1_CH, r1 - c0);
    __syncthreads();
    { int e = tid & 31, h = tid >> 5;
      if (e < nc) w_lds[e*H1 + h] = alpha[(size_t)h*ETOT + c0 + e];
      if (tid < nc) s_lds[tid] = csr[c0 + tid]; }
    __syncthreads();
    for (int e = grp; e < nc; e += 4){
      int s = s_lds[e];
      float w = w_lds[e*H1 + hh];
      ushort4 hv = *(const ushort4*)(h1 + (size_t)s*C1 + fb);
      a0 += w*bf2f(hv.x); a1 += w*bf2f(hv.y); a2 += w*bf2f(hv.z); a3 += w*bf2f(hv.w);
    }
  }
  __syncthreads();
  if (grp > 0){
    float* p = &red[grp-1][(tid%96)*4];
    p[0]=a0; p[1]=a1; p[2]=a2; p[3]=a3;
  }
  __syncthreads();
  if (grp == 0){
    int base = tid*4;
    float4 b4 = *(const float4*)(bias + base);
    float v0 = a0 + red[0][base+0] + red[1][base+0] + red[2][base+0] + b4.x;
    float v1 = a1 + red[0][base+1] + red[1][base+1] + red[2][base+1] + b4.y;
    float v2 = a2 + red[0][base+2] + red[1][base+2] + red[2][base+2] + b4.z;
    float v3 = a3 + red[0][base+3] + red[1][base+3] + red[2][base+3] + b4.w;
    ushort4 o; o.x=f2bf(fmaxf(v0,0.f)); o.y=f2bf(fmaxf(v1,0.f));
    o.z=f2bf(fmaxf(v2,0.f)); o.w=f2bf(fmaxf(v3,0.f));
    *(ushort4*)(out1 + (size_t)d*C1 + base) = o;
  }
}

// ---------- conv2 aggregation: 64 threads/dst ----------
#define AGG2_CH 64
__global__ __launch_bounds__(64) void agg2_kernel(const int* __restrict__ rowptr,
    const int* __restrict__ csr, const unsigned short* __restrict__ h2,
    const float* __restrict__ alpha, const float* __restrict__ bias,
    float* __restrict__ out2){
  int d = blockIdx.x, tid = threadIdx.x;
  int r0 = rowptr[d], r1 = rowptr[d+1];
  __shared__ float w_lds[AGG2_CH];
  __shared__ int   s_lds[AGG2_CH];
  __shared__ float red[3][C2];
  int grp = tid >> 4;            // 0..3
  int fb  = (tid & 15) * 4;      // features fb..fb+3
  float a0=0.f, a1=0.f, a2=0.f, a3=0.f;
  for (int c0 = r0; c0 < r1; c0 += AGG2_CH){
    int nc = min(AGG2_CH, r1 - c0);
    __syncthreads();
    if (tid < nc){ w_lds[tid] = alpha[c0 + tid]; s_lds[tid] = csr[c0 + tid]; }
    __syncthreads();
    for (int e = grp; e < nc; e += 4){
      int s = s_lds[e];
      float w = w_lds[e];
      ushort4 hv = *(const ushort4*)(h2 + (size_t)s*C2 + fb);
      a0 += w*bf2f(hv.x); a1 += w*bf2f(hv.y); a2 += w*bf2f(hv.z); a3 += w*bf2f(hv.w);
    }
  }
  __syncthreads();
  if (grp > 0){
    float* p = &red[grp-1][(tid&15)*4];
    p[0]=a0; p[1]=a1; p[2]=a2; p[3]=a3;
  }
  __syncthreads();
  if (grp == 0){
    int base = tid*4;
    float4 b4 = *(const float4*)(bias + base);
    float4 o;
    o.x = a0 + red[0][base+0] + red[1][base+0] + red[2][base+0] + b4.x;
    o.y = a1 + red[0][base+1] + red[1][base+1] + red[2][base+1] + b4.y;
    o.z = a2 + red[0][base+2] + red[1][base+2] + red[2][base+2] + b4.z;
    o.w = a3 + red[0][base+3] + red[1][base+3] + red[2][base+3] + b4.w;
    *(float4*)(out2 + (size_t)d*C2 + base) = o;
  }
}

// ---------- mean pool ----------
__global__ void pool_kernel(const float* __restrict__ out2, const int* __restrict__ batch,
                            float* __restrict__ sums, int* __restrict__ cnt){
  int i = blockIdx.x*blockDim.x + threadIdx.x;
  if (i >= N_NODES*C2) return;
  int n = i >> 6, f = i & 63;
  int g = batch[n];
  atomicAdd(&sums[g*C2 + f], out2[i]);
  if (f == 0) atomicAdd(&cnt[g], 1);
}
__global__ void finalize_kernel(const float* __restrict__ sums, const int* __restrict__ cnt,
                                float* __restrict__ out){
  int i = blockIdx.x*blockDim.x + threadIdx.x;
  if (i >= G_GRAPHS*C2) return;
  int g = i >> 6;
  out[i] = sums[i] / fmaxf((float)cnt[g], 1.f);
}

// ---------- launch ----------
extern "C" void kernel_launch(void* const* d_in, const int* in_sizes, int n_in,
                              void* d_out, int out_size, void* d_ws, size_t ws_size,
                              hipStream_t stream) {
  const float* x        = (const float*)d_in[0];
  const int*   ei       = (const int*)  d_in[1];
  const int*   batch    = (const int*)  d_in[2];
  const float* W1       = (const float*)d_in[3];
  const float* att_src1 = (const float*)d_in[4];
  const float* att_dst1 = (const float*)d_in[5];
  const float* bias1    = (const float*)d_in[6];
  const float* W2       = (const float*)d_in[7];
  const float* att_src2 = (const float*)d_in[8];
  const float* att_dst2 = (const float*)d_in[9];
  const float* bias2    = (const float*)d_in[10];
  float* out = (float*)d_out;

  char* ws = (char*)d_ws;
  size_t o = 0;
  auto alloc = [&](size_t bytes)->size_t{ size_t r=o; o=(o+bytes+255)&~(size_t)255; return r; };

  size_t xb_o     = alloc((size_t)N_NODES*F_IN*2);       // 12.8 MB
  size_t w1t_o    = alloc((size_t)C1*F_IN*2);
  size_t w2t_o    = alloc((size_t)C2*C1*2);
  size_t h1_o     = alloc((size_t)N_NODES*C1*2);         // 38.4 MB
  size_t out1_o   = alloc((size_t)N_NODES*C1*2);         // 38.4 MB
  size_t h2_o     = alloc((size_t)N_NODES*C2*2);         // 6.4 MB
  size_t out2_o   = alloc((size_t)N_NODES*C2*4);         // 12.8 MB
  size_t asrc1_o  = alloc((size_t)N_NODES*H1*4);
  size_t adst1_o  = alloc((size_t)N_NODES*H1*4);
  size_t asrc2_o  = alloc((size_t)N_NODES*4);
  size_t adst2_o  = alloc((size_t)N_NODES*4);
  size_t alpha1_o = alloc((size_t)H1*ETOT*4);            // 40.8 MB
  size_t alpha2_o = alloc((size_t)ETOT*4);               // 3.4 MB
  size_t zero_beg = o;
  size_t counts_o = alloc((size_t)N_NODES*4);
  size_t pool_o   = alloc((size_t)G_GRAPHS*C2*4);
  size_t cnt_o    = alloc((size_t)G_GRAPHS*4);
  size_t zero_end = o;
  size_t rowptr_o = alloc((size_t)(N_NODES+1)*4);
  size_t bsum_o   = alloc((size_t)NBLK_SCAN*4);
  size_t cursor_o = alloc((size_t)N_NODES*4);
  size_t csr_o    = alloc((size_t)ETOT*4);

  unsigned short* xb    = (unsigned short*)(ws + xb_o);
  unsigned short* w1t   = (unsigned short*)(ws + w1t_o);
  unsigned short* w2t   = (unsigned short*)(ws + w2t_o);
  unsigned short* h1b   = (unsigned short*)(ws + h1_o);
  unsigned short* out1b = (unsigned short*)(ws + out1_o);
  unsigned short* h2b   = (unsigned short*)(ws + h2_o);
  float* out2f  = (float*)(ws + out2_o);
  float* asrc1  = (float*)(ws + asrc1_o);
  float* adst1  = (float*)(ws + adst1_o);
  float* asrc2  = (float*)(ws + asrc2_o);
  float* adst2  = (float*)(ws + adst2_o);
  float* alpha1 = (float*)(ws + alpha1_o);
  float* alpha2 = (float*)(ws + alpha2_o);
  int*   counts = (int*)  (ws + counts_o);
  float* poolf  = (float*)(ws + pool_o);
  int*   cnt    = (int*)  (ws + cnt_o);
  int*   rowptr = (int*)  (ws + rowptr_o);
  int*   bsum   = (int*)  (ws + bsum_o);
  int*   cursor = (int*)  (ws + cursor_o);
  int*   csrsrc = (int*)  (ws + csr_o);

  hipMemsetAsync(ws + zero_beg, 0, zero_end - zero_beg, stream);

  const int TPB = 256;
  int egrid = (ETOT + TPB - 1)/TPB;

  // prep casts
  cast_x_kernel<<<(N_NODES*F_IN/4 + TPB-1)/TPB, TPB, 0, stream>>>(x, xb);
  transpose_w_kernel<<<(F_IN*C1 + TPB-1)/TPB, TPB, 0, stream>>>(W1, w1t, F_IN, C1);
  transpose_w_kernel<<<(C1*C2 + TPB-1)/TPB, TPB, 0, stream>>>(W2, w2t, C1, C2);

  // CSR build
  count_kernel<<<egrid, TPB, 0, stream>>>(ei, counts);
  scan_pass1<<<NBLK_SCAN, SCAN_B, 0, stream>>>(counts, rowptr, bsum);
  scan_pass2<<<1, 64, 0, stream>>>(bsum);
  scan_pass3<<<(N_NODES + TPB)/TPB, TPB, 0, stream>>>(rowptr, bsum, cursor);
  scatter_kernel<<<egrid, TPB, 0, stream>>>(ei, cursor, csrsrc);

  // conv1
  gemm_mfma<128,128,64,64><<<dim3((N_NODES+127)/128, C1/128), 256, 0, stream>>>(xb, w1t, h1b, N_NODES, C1, F_IN);
  a1_kernel<<<(N_NODES*H1 + TPB-1)/TPB, TPB, 0, stream>>>(h1b, att_src1, att_dst1, asrc1, adst1);
  alpha_kernel<H1><<<N_NODES, 64, 0, stream>>>(rowptr, csrsrc, asrc1, adst1, alpha1);
  agg1_kernel<<<N_NODES, 384, 0, stream>>>(rowptr, csrsrc, h1b, alpha1, bias1, out1b);

  // conv2
  gemm_mfma<128,64,64,32><<<dim3((N_NODES+127)/128, 1), 256, 0, stream>>>(out1b, w2t, h2b, N_NODES, C2, C1);
  a2_kernel<<<(N_NODES + TPB-1)/TPB, TPB, 0, stream>>>(h2b, att_src2, att_dst2, asrc2, adst2);
  alpha_kernel<1><<<N_NODES, 64, 0, stream>>>(rowptr, csrsrc, asrc2, adst2, alpha2);
  agg2_kernel<<<N_NODES, 64, 0, stream>>>(rowptr, csrsrc, h2b, alpha2, bias2, out2f);

  // pool
  pool_kernel<<<(N_NODES*C2 + TPB-1)/TPB, TPB, 0, stream>>>(out2f, batch, poolf, cnt);
  finalize_kernel<<<(G_GRAPHS*C2 + TPB-1)/TPB, TPB, 0, stream>>>(poolf, cnt, out);
}

// Round 4
// 510.423 us; speedup vs baseline: 3.9264x; 1.2544x over previous
//
#include <hip/hip_runtime.h>

#define N_NODES 50000
#define N_EDGES 800000
#define ETOT (N_EDGES + N_NODES)   // 850000
#define G_GRAPHS 256
#define F_IN 128
#define H1 12
#define D1 32
#define C1 (H1*D1)   // 384
#define C2 64
#define NEG 0.2f
#define SCAN_B 1024
#define NBLK_SCAN ((N_NODES + SCAN_B - 1)/SCAN_B)   // 49

using bf16x8  = __attribute__((ext_vector_type(8))) short;
using ushort8 = __attribute__((ext_vector_type(8))) unsigned short;
using f32x4   = __attribute__((ext_vector_type(4))) float;

__device__ __forceinline__ float lrelu(float x){ return x > 0.f ? x : NEG*x; }
__device__ __forceinline__ unsigned short f2bf(float f){
  unsigned u = __float_as_uint(f);
  u += 0x7fffu + ((u >> 16) & 1u);
  return (unsigned short)(u >> 16);
}
__device__ __forceinline__ float bf2f(unsigned short h){
  return __uint_as_float(((unsigned)h) << 16);
}

// ---------- prep ----------
__global__ void cast_x_kernel(const float* __restrict__ x, unsigned short* __restrict__ xb){
  int i = blockIdx.x*blockDim.x + threadIdx.x;
  int base = i*4;
  if (base >= N_NODES*F_IN) return;
  float4 v = *(const float4*)(x + base);
  ushort4 o; o.x=f2bf(v.x); o.y=f2bf(v.y); o.z=f2bf(v.z); o.w=f2bf(v.w);
  *(ushort4*)(xb + base) = o;
}
// W[K][Nc] fp32 -> Wt[Nc][K] bf16
__global__ void transpose_w_kernel(const float* __restrict__ W, unsigned short* __restrict__ Wt,
                                   int K, int Nc){
  int i = blockIdx.x*blockDim.x + threadIdx.x;
  if (i >= K*Nc) return;
  int n = i / K, k = i % K;
  Wt[i] = f2bf(W[(size_t)k*Nc + n]);
}
// wAb[c][k] bf16, c<12: W1·att_src (head c); 12<=c<24: W1·att_dst; else 0
__global__ void wab_prep(const float* __restrict__ W1, const float* __restrict__ att_src,
                         const float* __restrict__ att_dst, unsigned short* __restrict__ wAb){
  int i = blockIdx.x*blockDim.x + threadIdx.x;
  if (i >= 32*F_IN) return;
  int c = i >> 7, k = i & 127;
  float v = 0.f;
  if (c < 12){
    #pragma unroll
    for (int dd=0; dd<D1; ++dd) v += W1[(size_t)k*C1 + c*D1 + dd] * att_src[c*D1 + dd];
  } else if (c < 24){
    int h = c - 12;
    #pragma unroll
    for (int dd=0; dd<D1; ++dd) v += W1[(size_t)k*C1 + h*D1 + dd] * att_dst[h*D1 + dd];
  }
  wAb[i] = f2bf(v);
}

// ---------- bf16 MFMA GEMM: C[M][N] = A[M][K] @ Bt[N][K]^T ----------
template<int BM,int BN,int WM,int WN,bool F32OUT>
__global__ __launch_bounds__(256) void gemm_mfma(const unsigned short* __restrict__ A,
    const unsigned short* __restrict__ Bt, void* __restrict__ Cv,
    int M, int N, int K){
  constexpr int BK = 32;
  __shared__ unsigned short As2[4][BM][8];
  __shared__ unsigned short Bs2[4][BN][8];
  const int tid  = threadIdx.x;
  const int wid  = tid >> 6, lane = tid & 63;
  constexpr int NWX = BN / WN;
  const int wrow = (wid / NWX) * WM, wcol = (wid % NWX) * WN;
  constexpr int MR = WM/16, NR = WN/16;
  const int row0 = blockIdx.x * BM, col0 = blockIdx.y * BN;
  const int r = lane & 15, koct = lane >> 4;
  f32x4 acc[MR][NR];
  #pragma unroll
  for (int m=0;m<MR;m++)
    #pragma unroll
    for (int n=0;n<NR;n++) acc[m][n] = f32x4{0.f,0.f,0.f,0.f};

  for (int k0 = 0; k0 < K; k0 += BK){
    for (int s = tid; s < BM*8; s += 256){
      int rr = s >> 3, cc = (s & 7) * 4;
      int gr = row0 + rr;
      ushort4 v = (gr < M) ? *(const ushort4*)(A + (size_t)gr*K + k0 + cc)
                           : ushort4{0,0,0,0};
      *(ushort4*)(&As2[cc>>3][rr][cc&7]) = v;
    }
    for (int s = tid; s < BN*8; s += 256){
      int rr = s >> 3, cc = (s & 7) * 4;
      ushort4 v = *(const ushort4*)(Bt + (size_t)(col0+rr)*K + k0 + cc);
      *(ushort4*)(&Bs2[cc>>3][rr][cc&7]) = v;
    }
    __syncthreads();
    bf16x8 af[MR], bq[NR];
    #pragma unroll
    for (int m=0;m<MR;m++) af[m] = *(const bf16x8*)(&As2[koct][wrow + m*16 + r][0]);
    #pragma unroll
    for (int n=0;n<NR;n++) bq[n] = *(const bf16x8*)(&Bs2[koct][wcol + n*16 + r][0]);
    #pragma unroll
    for (int m=0;m<MR;m++)
      #pragma unroll
      for (int n=0;n<NR;n++)
        acc[m][n] = __builtin_amdgcn_mfma_f32_16x16x32_bf16(af[m], bq[n], acc[m][n], 0,0,0);
    __syncthreads();
  }
  #pragma unroll
  for (int m=0;m<MR;m++){
    #pragma unroll
    for (int rr=0; rr<4; rr++){
      int grow = row0 + wrow + m*16 + koct*4 + rr;
      if (grow < M){
        #pragma unroll
        for (int n=0;n<NR;n++){
          if constexpr (F32OUT)
            ((float*)Cv)[(size_t)grow*N + col0 + wcol + n*16 + r] = acc[m][n][rr];
          else
            ((unsigned short*)Cv)[(size_t)grow*N + col0 + wcol + n*16 + r] = f2bf(acc[m][n][rr]);
        }
      }
    }
  }
}

// ---------- CSR build ----------
__global__ void count_kernel(const int* __restrict__ ei, int* __restrict__ counts){
  int e = blockIdx.x*blockDim.x + threadIdx.x;
  if (e >= ETOT) return;
  int d = (e < N_EDGES) ? ei[N_EDGES + e] : (e - N_EDGES);
  atomicAdd(&counts[d], 1);
}
__global__ __launch_bounds__(SCAN_B) void scan_pass1(const int* __restrict__ counts,
    int* __restrict__ excl, int* __restrict__ bsum){
  __shared__ int sdata[SCAN_B];
  int i = blockIdx.x*SCAN_B + threadIdx.x;
  int v = (i < N_NODES) ? counts[i] : 0;
  sdata[threadIdx.x] = v;
  __syncthreads();
  for (int off=1; off<SCAN_B; off<<=1){
    int t = (threadIdx.x >= off) ? sdata[threadIdx.x-off] : 0;
    __syncthreads();
    sdata[threadIdx.x] += t;
    __syncthreads();
  }
  if (i < N_NODES) excl[i] = sdata[threadIdx.x] - v;
  if (threadIdx.x == SCAN_B-1) bsum[blockIdx.x] = sdata[SCAN_B-1];
}
__global__ void scan_pass2(int* __restrict__ bsum){
  if (threadIdx.x == 0){
    int acc = 0;
    for (int b=0;b<NBLK_SCAN;b++){ int t = bsum[b]; bsum[b] = acc; acc += t; }
  }
}
__global__ void scan_pass3(int* __restrict__ rowptr, const int* __restrict__ bsum,
                           int* __restrict__ cursor){
  int i = blockIdx.x*blockDim.x + threadIdx.x;
  if (i < N_NODES){
    int r = rowptr[i] + bsum[i/SCAN_B];
    rowptr[i] = r; cursor[i] = r;
  }
  if (i == N_NODES) rowptr[N_NODES] = ETOT;
}
__global__ void scatter_kernel(const int* __restrict__ ei, int* __restrict__ cursor,
                               int* __restrict__ csr_src){
  int e = blockIdx.x*blockDim.x + threadIdx.x;
  if (e >= ETOT) return;
  int s, d;
  if (e < N_EDGES){ s = ei[e]; d = ei[N_EDGES + e]; } else { s = d = e - N_EDGES; }
  int slot = atomicAdd(&cursor[d], 1);
  csr_src[slot] = s;
}

// ---------- alpha (conv1, 12 heads): 1 wave per dst, edge-per-lane ----------
__global__ __launch_bounds__(64) void alpha1_kernel(const int* __restrict__ rowptr,
    const int* __restrict__ csr, const float* __restrict__ asd,
    float* __restrict__ alpha){
  int d = blockIdx.x, lane = threadIdx.x;
  int r0 = rowptr[d], r1 = rowptr[d+1], deg = r1 - r0;
  float4 ad0 = *(const float4*)(asd + (size_t)d*32 + 12);
  float4 ad1 = *(const float4*)(asd + (size_t)d*32 + 16);
  float4 ad2 = *(const float4*)(asd + (size_t)d*32 + 20);
  float ad[12] = {ad0.x,ad0.y,ad0.z,ad0.w, ad1.x,ad1.y,ad1.z,ad1.w, ad2.x,ad2.y,ad2.z,ad2.w};

  if (deg <= 64){
    bool act = lane < deg;
    int j = r0 + lane;
    int s = act ? csr[j] : 0;
    float4 s0 = *(const float4*)(asd + (size_t)s*32);
    float4 s1 = *(const float4*)(asd + (size_t)s*32 + 4);
    float4 s2 = *(const float4*)(asd + (size_t)s*32 + 8);
    float as[12] = {s0.x,s0.y,s0.z,s0.w, s1.x,s1.y,s1.z,s1.w, s2.x,s2.y,s2.z,s2.w};
    float w[12];
    #pragma unroll
    for (int h=0; h<12; ++h){
      float l = act ? lrelu(as[h] + ad[h]) : -1e30f;
      float m = l;
      #pragma unroll
      for (int off=32; off; off>>=1) m = fmaxf(m, __shfl_xor(m, off));
      float wv = act ? __expf(l - m) : 0.f;
      float ss = wv;
      #pragma unroll
      for (int off=32; off; off>>=1) ss += __shfl_xor(ss, off);
      w[h] = wv / ss;
    }
    if (act){
      float4 o0 = {w[0],w[1],w[2],w[3]};
      float4 o1 = {w[4],w[5],w[6],w[7]};
      float4 o2 = {w[8],w[9],w[10],w[11]};
      *(float4*)(alpha + (size_t)j*12)     = o0;
      *(float4*)(alpha + (size_t)j*12 + 4) = o1;
      *(float4*)(alpha + (size_t)j*12 + 8) = o2;
    }
  } else {
    float mx[12], ss[12];
    #pragma unroll
    for (int h=0;h<12;h++){ mx[h] = -1e30f; ss[h] = 0.f; }
    for (int j = r0 + lane; j < r1; j += 64){
      int s = csr[j];
      float4 s0 = *(const float4*)(asd + (size_t)s*32);
      float4 s1 = *(const float4*)(asd + (size_t)s*32 + 4);
      float4 s2 = *(const float4*)(asd + (size_t)s*32 + 8);
      float as[12] = {s0.x,s0.y,s0.z,s0.w, s1.x,s1.y,s1.z,s1.w, s2.x,s2.y,s2.z,s2.w};
      #pragma unroll
      for (int h=0;h<12;h++) mx[h] = fmaxf(mx[h], lrelu(as[h] + ad[h]));
    }
    #pragma unroll
    for (int h=0;h<12;h++){
      #pragma unroll
      for (int off=32; off; off>>=1) mx[h] = fmaxf(mx[h], __shfl_xor(mx[h], off));
    }
    for (int j = r0 + lane; j < r1; j += 64){
      int s = csr[j];
      float4 s0 = *(const float4*)(asd + (size_t)s*32);
      float4 s1 = *(const float4*)(asd + (size_t)s*32 + 4);
      float4 s2 = *(const float4*)(asd + (size_t)s*32 + 8);
      float as[12] = {s0.x,s0.y,s0.z,s0.w, s1.x,s1.y,s1.z,s1.w, s2.x,s2.y,s2.z,s2.w};
      float w[12];
      #pragma unroll
      for (int h=0;h<12;h++){ w[h] = __expf(lrelu(as[h]+ad[h]) - mx[h]); ss[h] += w[h]; }
      float4 o0 = {w[0],w[1],w[2],w[3]};
      float4 o1 = {w[4],w[5],w[6],w[7]};
      float4 o2 = {w[8],w[9],w[10],w[11]};
      *(float4*)(alpha + (size_t)j*12)     = o0;
      *(float4*)(alpha + (size_t)j*12 + 4) = o1;
      *(float4*)(alpha + (size_t)j*12 + 8) = o2;
    }
    float inv[12];
    #pragma unroll
    for (int h=0;h<12;h++){
      #pragma unroll
      for (int off=32; off; off>>=1) ss[h] += __shfl_xor(ss[h], off);
      inv[h] = 1.f / ss[h];
    }
    for (int j = r0 + lane; j < r1; j += 64){
      float4 o0 = *(const float4*)(alpha + (size_t)j*12);
      float4 o1 = *(const float4*)(alpha + (size_t)j*12 + 4);
      float4 o2 = *(const float4*)(alpha + (size_t)j*12 + 8);
      o0.x*=inv[0]; o0.y*=inv[1]; o0.z*=inv[2]; o0.w*=inv[3];
      o1.x*=inv[4]; o1.y*=inv[5]; o1.z*=inv[6]; o1.w*=inv[7];
      o2.x*=inv[8]; o2.y*=inv[9]; o2.z*=inv[10]; o2.w*=inv[11];
      *(float4*)(alpha + (size_t)j*12)     = o0;
      *(float4*)(alpha + (size_t)j*12 + 4) = o1;
      *(float4*)(alpha + (size_t)j*12 + 8) = o2;
    }
  }
}

// ---------- alpha (conv2, 1 head) ----------
__global__ __launch_bounds__(64) void alpha2_kernel(const int* __restrict__ rowptr,
    const int* __restrict__ csr, const float* __restrict__ asrc,
    const float* __restrict__ adst, float* __restrict__ alpha){
  int d = blockIdx.x, lane = threadIdx.x;
  int r0 = rowptr[d], r1 = rowptr[d+1], deg = r1 - r0;
  float ad = adst[d];
  if (deg <= 64){
    bool act = lane < deg;
    int j = r0 + lane;
    int s = act ? csr[j] : 0;
    float l = act ? lrelu(asrc[s] + ad) : -1e30f;
    float m = l;
    #pragma unroll
    for (int off=32; off; off>>=1) m = fmaxf(m, __shfl_xor(m, off));
    float wv = act ? __expf(l - m) : 0.f;
    float ss = wv;
    #pragma unroll
    for (int off=32; off; off>>=1) ss += __shfl_xor(ss, off);
    if (act) alpha[j] = wv / ss;
  } else {
    float mx = -1e30f, ss = 0.f;
    for (int j = r0 + lane; j < r1; j += 64){
      int s = csr[j];
      mx = fmaxf(mx, lrelu(asrc[s] + ad));
    }
    #pragma unroll
    for (int off=32; off; off>>=1) mx = fmaxf(mx, __shfl_xor(mx, off));
    for (int j = r0 + lane; j < r1; j += 64){
      int s = csr[j];
      float w = __expf(lrelu(asrc[s] + ad) - mx);
      ss += w; alpha[j] = w;
    }
    #pragma unroll
    for (int off=32; off; off>>=1) ss += __shfl_xor(ss, off);
    float inv = 1.f / ss;
    for (int j = r0 + lane; j < r1; j += 64)
      alpha[j] *= inv;
  }
}

// ---------- conv1: x-space aggregation + fused per-head MFMA transform ----------
// 16 dst/block, 16 lanes/dst; acc[12][8] f32/thread; then agg(bf16,LDS) @ W1_h via MFMA
__global__ __launch_bounds__(256) void agg1x_kernel(const int* __restrict__ rowptr,
    const int* __restrict__ csr, const unsigned short* __restrict__ xb,
    const float* __restrict__ alpha, const unsigned short* __restrict__ w1t,
    const float* __restrict__ bias, unsigned short* __restrict__ out1){
  constexpr int ROWE = H1*F_IN + 8;   // 1544 (pad 8 elems)
  __shared__ unsigned short agg[16*ROWE];
  int tid = threadIdx.x;
  int g = tid >> 4, t16 = tid & 15;
  int d = blockIdx.x*16 + g;
  int r0 = rowptr[d], r1 = rowptr[d+1];
  float acc[12][8];
  #pragma unroll
  for (int h=0;h<12;h++)
    #pragma unroll
    for (int i=0;i<8;i++) acc[h][i] = 0.f;

  float4 a0={0,0,0,0}, a1={0,0,0,0}, a2={0,0,0,0};
  ushort8 xv = {0,0,0,0,0,0,0,0};
  if (r0 < r1){
    int s = csr[r0];
    a0 = *(const float4*)(alpha + (size_t)r0*12);
    a1 = *(const float4*)(alpha + (size_t)r0*12 + 4);
    a2 = *(const float4*)(alpha + (size_t)r0*12 + 8);
    xv = *(const ushort8*)(xb + (size_t)s*F_IN + t16*8);
  }
  for (int j = r0; j < r1; ++j){
    float4 c0=a0, c1=a1, c2=a2; ushort8 cx=xv;
    if (j+1 < r1){
      int s = csr[j+1];
      a0 = *(const float4*)(alpha + (size_t)(j+1)*12);
      a1 = *(const float4*)(alpha + (size_t)(j+1)*12 + 4);
      a2 = *(const float4*)(alpha + (size_t)(j+1)*12 + 8);
      xv = *(const ushort8*)(xb + (size_t)s*F_IN + t16*8);
    }
    float xf[8];
    #pragma unroll
    for (int i=0;i<8;i++) xf[i] = bf2f((unsigned short)cx[i]);
    float aw[12] = {c0.x,c0.y,c0.z,c0.w, c1.x,c1.y,c1.z,c1.w, c2.x,c2.y,c2.z,c2.w};
    #pragma unroll
    for (int h=0;h<12;h++)
      #pragma unroll
      for (int i=0;i<8;i++) acc[h][i] += aw[h]*xf[i];
  }
  // stage aggregated x (bf16) to LDS
  #pragma unroll
  for (int h=0;h<12;h++){
    ushort8 v;
    #pragma unroll
    for (int i=0;i<8;i++) v[i] = f2bf(acc[h][i]);
    *(ushort8*)(&agg[g*ROWE + h*F_IN + t16*8]) = v;
  }
  __syncthreads();
  // transform: out1[d, h*32+c] = agg[d,h,:] @ W1[:, h*32+c]; 4 waves x 3 heads
  int wid = tid >> 6, lane = tid & 63;
  int r = lane & 15, q = lane >> 4;
  for (int hh = 0; hh < 3; ++hh){
    int h = wid*3 + hh;
    #pragma unroll
    for (int nb=0; nb<2; ++nb){
      f32x4 c = {0.f,0.f,0.f,0.f};
      #pragma unroll
      for (int kk=0; kk<4; ++kk){
        bf16x8 af = *(const bf16x8*)(&agg[r*ROWE + h*F_IN + kk*32 + q*8]);
        bf16x8 bq = *(const bf16x8*)(w1t + (size_t)(h*32 + nb*16 + r)*F_IN + kk*32 + q*8);
        c = __builtin_amdgcn_mfma_f32_16x16x32_bf16(af, bq, c, 0,0,0);
      }
      int col = h*32 + nb*16 + r;
      float bv = bias[col];
      #pragma unroll
      for (int rr=0; rr<4; ++rr){
        int drow = q*4 + rr;
        int od = blockIdx.x*16 + drow;
        float v = fmaxf(c[rr] + bv, 0.f);
        out1[(size_t)od*C1 + col] = f2bf(v);
      }
    }
  }
}

// ---------- per-node attention halves, conv2 ----------
__global__ void a2_kernel(const unsigned short* __restrict__ h2,
    const float* __restrict__ att_src, const float* __restrict__ att_dst,
    float* __restrict__ a_src, float* __restrict__ a_dst){
  int n = blockIdx.x*blockDim.x + threadIdx.x;
  if (n >= N_NODES) return;
  const unsigned short* hp = h2 + (size_t)n*C2;
  float s=0.f, d=0.f;
  #pragma unroll
  for (int k4=0;k4<16;k4++){
    ushort4 v = *(const ushort4*)(hp + k4*4);
    int b = k4*4;
    s += bf2f(v.x)*att_src[b] + bf2f(v.y)*att_src[b+1] + bf2f(v.z)*att_src[b+2] + bf2f(v.w)*att_src[b+3];
    d += bf2f(v.x)*att_dst[b] + bf2f(v.y)*att_dst[b+1] + bf2f(v.z)*att_dst[b+2] + bf2f(v.w)*att_dst[b+3];
  }
  a_src[n]=s; a_dst[n]=d;
}

// ---------- conv2 aggregation + fused mean-pool atomics ----------
#define AGG2_CH 64
__global__ __launch_bounds__(64) void agg2_pool(const int* __restrict__ rowptr,
    const int* __restrict__ csr, const unsigned short* __restrict__ h2,
    const float* __restrict__ alpha, const float* __restrict__ bias,
    const int* __restrict__ batch, float* __restrict__ pool){
  int d = blockIdx.x, tid = threadIdx.x;
  int r0 = rowptr[d], r1 = rowptr[d+1];
  __shared__ float w_lds[AGG2_CH];
  __shared__ int   s_lds[AGG2_CH];
  __shared__ float red[3][C2];
  int grp = tid >> 4;
  int fb  = (tid & 15) * 4;
  float a0=0.f, a1=0.f, a2=0.f, a3=0.f;
  for (int c0 = r0; c0 < r1; c0 += AGG2_CH){
    int nc = min(AGG2_CH, r1 - c0);
    __syncthreads();
    if (tid < nc){ w_lds[tid] = alpha[c0 + tid]; s_lds[tid] = csr[c0 + tid]; }
    __syncthreads();
    for (int e = grp; e < nc; e += 4){
      int s = s_lds[e];
      float w = w_lds[e];
      ushort4 hv = *(const ushort4*)(h2 + (size_t)s*C2 + fb);
      a0 += w*bf2f(hv.x); a1 += w*bf2f(hv.y); a2 += w*bf2f(hv.z); a3 += w*bf2f(hv.w);
    }
  }
  __syncthreads();
  if (grp > 0){
    float* p = &red[grp-1][fb];
    p[0]=a0; p[1]=a1; p[2]=a2; p[3]=a3;
  }
  __syncthreads();
  if (grp == 0){
    int g = batch[d];
    float4 b4 = *(const float4*)(bias + fb);
    float v0 = a0 + red[0][fb+0] + red[1][fb+0] + red[2][fb+0] + b4.x;
    float v1 = a1 + red[0][fb+1] + red[1][fb+1] + red[2][fb+1] + b4.y;
    float v2 = a2 + red[0][fb+2] + red[1][fb+2] + red[2][fb+2] + b4.z;
    float v3 = a3 + red[0][fb+3] + red[1][fb+3] + red[2][fb+3] + b4.w;
    atomicAdd(&pool[g*C2 + fb+0], v0);
    atomicAdd(&pool[g*C2 + fb+1], v1);
    atomicAdd(&pool[g*C2 + fb+2], v2);
    atomicAdd(&pool[g*C2 + fb+3], v3);
  }
}

__global__ void cnt_kernel(const int* __restrict__ batch, int* __restrict__ cnt){
  int n = blockIdx.x*blockDim.x + threadIdx.x;
  if (n < N_NODES) atomicAdd(&cnt[batch[n]], 1);
}
__global__ void finalize_kernel(const float* __restrict__ sums, const int* __restrict__ cnt,
                                float* __restrict__ out){
  int i = blockIdx.x*blockDim.x + threadIdx.x;
  if (i >= G_GRAPHS*C2) return;
  int g = i >> 6;
  out[i] = sums[i] / fmaxf((float)cnt[g], 1.f);
}

// ---------- launch ----------
extern "C" void kernel_launch(void* const* d_in, const int* in_sizes, int n_in,
                              void* d_out, int out_size, void* d_ws, size_t ws_size,
                              hipStream_t stream) {
  const float* x        = (const float*)d_in[0];
  const int*   ei       = (const int*)  d_in[1];
  const int*   batch    = (const int*)  d_in[2];
  const float* W1       = (const float*)d_in[3];
  const float* att_src1 = (const float*)d_in[4];
  const float* att_dst1 = (const float*)d_in[5];
  const float* bias1    = (const float*)d_in[6];
  const float* W2       = (const float*)d_in[7];
  const float* att_src2 = (const float*)d_in[8];
  const float* att_dst2 = (const float*)d_in[9];
  const float* bias2    = (const float*)d_in[10];
  float* out = (float*)d_out;

  char* ws = (char*)d_ws;
  size_t o = 0;
  auto alloc = [&](size_t bytes)->size_t{ size_t r=o; o=(o+bytes+255)&~(size_t)255; return r; };

  size_t xb_o     = alloc((size_t)N_NODES*F_IN*2);   // 12.8 MB
  size_t w1t_o    = alloc((size_t)C1*F_IN*2);
  size_t w2t_o    = alloc((size_t)C2*C1*2);
  size_t wab_o    = alloc((size_t)32*F_IN*2);
  size_t asd_o    = alloc((size_t)N_NODES*32*4);     // 6.4 MB (src:0-11, dst:12-23)
  size_t out1_o   = alloc((size_t)N_NODES*C1*2);     // 38.4 MB
  size_t h2_o     = alloc((size_t)N_NODES*C2*2);     // 6.4 MB
  size_t asrc2_o  = alloc((size_t)N_NODES*4);
  size_t adst2_o  = alloc((size_t)N_NODES*4);
  size_t alpha1_o = alloc((size_t)ETOT*H1*4);        // 40.8 MB
  size_t alpha2_o = alloc((size_t)ETOT*4);
  size_t zero_beg = o;
  size_t counts_o = alloc((size_t)N_NODES*4);
  size_t pool_o   = alloc((size_t)G_GRAPHS*C2*4);
  size_t cnt_o    = alloc((size_t)G_GRAPHS*4);
  size_t zero_end = o;
  size_t rowptr_o = alloc((size_t)(N_NODES+1)*4);
  size_t bsum_o   = alloc((size_t)NBLK_SCAN*4);
  size_t cursor_o = alloc((size_t)N_NODES*4);
  size_t csr_o    = alloc((size_t)ETOT*4);

  unsigned short* xb    = (unsigned short*)(ws + xb_o);
  unsigned short* w1t   = (unsigned short*)(ws + w1t_o);
  unsigned short* w2t   = (unsigned short*)(ws + w2t_o);
  unsigned short* wab   = (unsigned short*)(ws + wab_o);
  float* asd    = (float*)(ws + asd_o);
  unsigned short* out1b = (unsigned short*)(ws + out1_o);
  unsigned short* h2b   = (unsigned short*)(ws + h2_o);
  float* asrc2  = (float*)(ws + asrc2_o);
  float* adst2  = (float*)(ws + adst2_o);
  float* alpha1 = (float*)(ws + alpha1_o);
  float* alpha2 = (float*)(ws + alpha2_o);
  int*   counts = (int*)  (ws + counts_o);
  float* poolf  = (float*)(ws + pool_o);
  int*   cnt    = (int*)  (ws + cnt_o);
  int*   rowptr = (int*)  (ws + rowptr_o);
  int*   bsum   = (int*)  (ws + bsum_o);
  int*   cursor = (int*)  (ws + cursor_o);
  int*   csrsrc = (int*)  (ws + csr_o);

  hipMemsetAsync(ws + zero_beg, 0, zero_end - zero_beg, stream);

  const int TPB = 256;
  int egrid = (ETOT + TPB - 1)/TPB;

  // prep
  cast_x_kernel<<<(N_NODES*F_IN/4 + TPB-1)/TPB, TPB, 0, stream>>>(x, xb);
  transpose_w_kernel<<<(F_IN*C1 + TPB-1)/TPB, TPB, 0, stream>>>(W1, w1t, F_IN, C1);
  transpose_w_kernel<<<(C1*C2 + TPB-1)/TPB, TPB, 0, stream>>>(W2, w2t, C1, C2);
  wab_prep<<<(32*F_IN + TPB-1)/TPB, TPB, 0, stream>>>(W1, att_src1, att_dst1, wab);

  // CSR build
  count_kernel<<<egrid, TPB, 0, stream>>>(ei, counts);
  scan_pass1<<<NBLK_SCAN, SCAN_B, 0, stream>>>(counts, rowptr, bsum);
  scan_pass2<<<1, 64, 0, stream>>>(bsum);
  scan_pass3<<<(N_NODES + TPB)/TPB, TPB, 0, stream>>>(rowptr, bsum, cursor);
  scatter_kernel<<<egrid, TPB, 0, stream>>>(ei, cursor, csrsrc);

  // conv1: attention logits via tiny MFMA GEMM (f32 out), then alpha, then x-space agg
  gemm_mfma<128,32,32,32,true><<<dim3((N_NODES+127)/128, 1), 256, 0, stream>>>(xb, wab, asd, N_NODES, 32, F_IN);
  alpha1_kernel<<<N_NODES, 64, 0, stream>>>(rowptr, csrsrc, asd, alpha1);
  agg1x_kernel<<<N_NODES/16, 256, 0, stream>>>(rowptr, csrsrc, xb, alpha1, w1t, bias1, out1b);

  // conv2
  gemm_mfma<128,64,64,32,false><<<dim3((N_NODES+127)/128, 1), 256, 0, stream>>>(out1b, w2t, h2b, N_NODES, C2, C1);
  a2_kernel<<<(N_NODES + TPB-1)/TPB, TPB, 0, stream>>>(h2b, att_src2, att_dst2, asrc2, adst2);
  alpha2_kernel<<<N_NODES, 64, 0, stream>>>(rowptr, csrsrc, asrc2, adst2, alpha2);
  agg2_pool<<<N_NODES, 64, 0, stream>>>(rowptr, csrsrc, h2b, alpha2, bias2, batch, poolf);

  // pool finalize
  cnt_kernel<<<(N_NODES + TPB-1)/TPB, TPB, 0, stream>>>(batch, cnt);
  finalize_kernel<<<(G_GRAPHS*C2 + TPB-1)/TPB, TPB, 0, stream>>>(poolf, cnt, out);
}

// Round 5
// 510.187 us; speedup vs baseline: 3.9282x; 1.0005x over previous
//
#include <hip/hip_runtime.h>

#define N_NODES 50000
#define N_EDGES 800000
#define ETOT (N_EDGES + N_NODES)   // 850000
#define G_GRAPHS 256
#define F_IN 128
#define H1 12
#define D1 32
#define C1 (H1*D1)   // 384
#define C2 64
#define NEG 0.2f
#define SCAN_B 1024
#define NBLK_SCAN ((N_NODES + SCAN_B - 1)/SCAN_B)   // 49

using bf16x8  = __attribute__((ext_vector_type(8))) short;
using ushort8 = __attribute__((ext_vector_type(8))) unsigned short;
using f32x4   = __attribute__((ext_vector_type(4))) float;

__device__ __forceinline__ float lrelu(float x){ return x > 0.f ? x : NEG*x; }
__device__ __forceinline__ unsigned short f2bf(float f){
  unsigned u = __float_as_uint(f);
  u += 0x7fffu + ((u >> 16) & 1u);
  return (unsigned short)(u >> 16);
}
__device__ __forceinline__ float bf2f(unsigned short h){
  return __uint_as_float(((unsigned)h) << 16);
}

// ---------- prep ----------
__global__ void cast_x_kernel(const float* __restrict__ x, unsigned short* __restrict__ xb){
  int i = blockIdx.x*blockDim.x + threadIdx.x;
  int base = i*4;
  if (base >= N_NODES*F_IN) return;
  float4 v = *(const float4*)(x + base);
  ushort4 o; o.x=f2bf(v.x); o.y=f2bf(v.y); o.z=f2bf(v.z); o.w=f2bf(v.w);
  *(ushort4*)(xb + base) = o;
}
// W[K][Nc] fp32 -> Wt[Nc][K] bf16
__global__ void transpose_w_kernel(const float* __restrict__ W, unsigned short* __restrict__ Wt,
                                   int K, int Nc){
  int i = blockIdx.x*blockDim.x + threadIdx.x;
  if (i >= K*Nc) return;
  int n = i / K, k = i % K;
  Wt[i] = f2bf(W[(size_t)k*Nc + n]);
}
// wAb[c][k] bf16, c<12: W1·att_src (head c); 12<=c<24: W1·att_dst; else 0
__global__ void wab_prep(const float* __restrict__ W1, const float* __restrict__ att_src,
                         const float* __restrict__ att_dst, unsigned short* __restrict__ wAb){
  int i = blockIdx.x*blockDim.x + threadIdx.x;
  if (i >= 32*F_IN) return;
  int c = i >> 7, k = i & 127;
  float v = 0.f;
  if (c < 12){
    #pragma unroll
    for (int dd=0; dd<D1; ++dd) v += W1[(size_t)k*C1 + c*D1 + dd] * att_src[c*D1 + dd];
  } else if (c < 24){
    int h = c - 12;
    #pragma unroll
    for (int dd=0; dd<D1; ++dd) v += W1[(size_t)k*C1 + h*D1 + dd] * att_dst[h*D1 + dd];
  }
  wAb[i] = f2bf(v);
}

// ---------- bf16 MFMA GEMM: C[M][N] = A[M][K] @ Bt[N][K]^T ----------
template<int BM,int BN,int WM,int WN,bool F32OUT>
__global__ __launch_bounds__(256) void gemm_mfma(const unsigned short* __restrict__ A,
    const unsigned short* __restrict__ Bt, void* __restrict__ Cv,
    int M, int N, int K){
  constexpr int BK = 32;
  __shared__ unsigned short As2[4][BM][8];
  __shared__ unsigned short Bs2[4][BN][8];
  const int tid  = threadIdx.x;
  const int wid  = tid >> 6, lane = tid & 63;
  constexpr int NWX = BN / WN;
  const int wrow = (wid / NWX) * WM, wcol = (wid % NWX) * WN;
  constexpr int MR = WM/16, NR = WN/16;
  const int row0 = blockIdx.x * BM, col0 = blockIdx.y * BN;
  const int r = lane & 15, koct = lane >> 4;
  f32x4 acc[MR][NR];
  #pragma unroll
  for (int m=0;m<MR;m++)
    #pragma unroll
    for (int n=0;n<NR;n++) acc[m][n] = f32x4{0.f,0.f,0.f,0.f};

  for (int k0 = 0; k0 < K; k0 += BK){
    for (int s = tid; s < BM*8; s += 256){
      int rr = s >> 3, cc = (s & 7) * 4;
      int gr = row0 + rr;
      ushort4 v = (gr < M) ? *(const ushort4*)(A + (size_t)gr*K + k0 + cc)
                           : ushort4{0,0,0,0};
      *(ushort4*)(&As2[cc>>3][rr][cc&7]) = v;
    }
    for (int s = tid; s < BN*8; s += 256){
      int rr = s >> 3, cc = (s & 7) * 4;
      ushort4 v = *(const ushort4*)(Bt + (size_t)(col0+rr)*K + k0 + cc);
      *(ushort4*)(&Bs2[cc>>3][rr][cc&7]) = v;
    }
    __syncthreads();
    bf16x8 af[MR], bq[NR];
    #pragma unroll
    for (int m=0;m<MR;m++) af[m] = *(const bf16x8*)(&As2[koct][wrow + m*16 + r][0]);
    #pragma unroll
    for (int n=0;n<NR;n++) bq[n] = *(const bf16x8*)(&Bs2[koct][wcol + n*16 + r][0]);
    #pragma unroll
    for (int m=0;m<MR;m++)
      #pragma unroll
      for (int n=0;n<NR;n++)
        acc[m][n] = __builtin_amdgcn_mfma_f32_16x16x32_bf16(af[m], bq[n], acc[m][n], 0,0,0);
    __syncthreads();
  }
  #pragma unroll
  for (int m=0;m<MR;m++){
    #pragma unroll
    for (int rr=0; rr<4; rr++){
      int grow = row0 + wrow + m*16 + koct*4 + rr;
      if (grow < M){
        #pragma unroll
        for (int n=0;n<NR;n++){
          if constexpr (F32OUT)
            ((float*)Cv)[(size_t)grow*N + col0 + wcol + n*16 + r] = acc[m][n][rr];
          else
            ((unsigned short*)Cv)[(size_t)grow*N + col0 + wcol + n*16 + r] = f2bf(acc[m][n][rr]);
        }
      }
    }
  }
}

// ---------- CSR build ----------
__global__ void count_kernel(const int* __restrict__ ei, int* __restrict__ counts){
  int e = blockIdx.x*blockDim.x + threadIdx.x;
  if (e >= ETOT) return;
  int d = (e < N_EDGES) ? ei[N_EDGES + e] : (e - N_EDGES);
  atomicAdd(&counts[d], 1);
}
__global__ __launch_bounds__(SCAN_B) void scan_pass1(const int* __restrict__ counts,
    int* __restrict__ excl, int* __restrict__ bsum){
  __shared__ int sdata[SCAN_B];
  int i = blockIdx.x*SCAN_B + threadIdx.x;
  int v = (i < N_NODES) ? counts[i] : 0;
  sdata[threadIdx.x] = v;
  __syncthreads();
  for (int off=1; off<SCAN_B; off<<=1){
    int t = (threadIdx.x >= off) ? sdata[threadIdx.x-off] : 0;
    __syncthreads();
    sdata[threadIdx.x] += t;
    __syncthreads();
  }
  if (i < N_NODES) excl[i] = sdata[threadIdx.x] - v;
  if (threadIdx.x == SCAN_B-1) bsum[blockIdx.x] = sdata[SCAN_B-1];
}
__global__ void scan_pass2(int* __restrict__ bsum){
  if (threadIdx.x == 0){
    int acc = 0;
    for (int b=0;b<NBLK_SCAN;b++){ int t = bsum[b]; bsum[b] = acc; acc += t; }
  }
}
__global__ void scan_pass3(int* __restrict__ rowptr, const int* __restrict__ bsum,
                           int* __restrict__ cursor){
  int i = blockIdx.x*blockDim.x + threadIdx.x;
  if (i < N_NODES){
    int r = rowptr[i] + bsum[i/SCAN_B];
    rowptr[i] = r; cursor[i] = r;
  }
  if (i == N_NODES) rowptr[N_NODES] = ETOT;
}
__global__ void scatter_kernel(const int* __restrict__ ei, int* __restrict__ cursor,
                               int* __restrict__ csr_src){
  int e = blockIdx.x*blockDim.x + threadIdx.x;
  if (e >= ETOT) return;
  int s, d;
  if (e < N_EDGES){ s = ei[e]; d = ei[N_EDGES + e]; } else { s = d = e - N_EDGES; }
  int slot = atomicAdd(&cursor[d], 1);
  csr_src[slot] = s;
}

// ---------- alpha (conv1, 12 heads): 1 wave per dst, edge-per-lane ----------
__global__ __launch_bounds__(64) void alpha1_kernel(const int* __restrict__ rowptr,
    const int* __restrict__ csr, const float* __restrict__ asd,
    float* __restrict__ alpha){
  int d = blockIdx.x, lane = threadIdx.x;
  int r0 = rowptr[d], r1 = rowptr[d+1], deg = r1 - r0;
  float4 ad0 = *(const float4*)(asd + (size_t)d*32 + 12);
  float4 ad1 = *(const float4*)(asd + (size_t)d*32 + 16);
  float4 ad2 = *(const float4*)(asd + (size_t)d*32 + 20);
  float ad[12] = {ad0.x,ad0.y,ad0.z,ad0.w, ad1.x,ad1.y,ad1.z,ad1.w, ad2.x,ad2.y,ad2.z,ad2.w};

  if (deg <= 64){
    bool act = lane < deg;
    int j = r0 + lane;
    int s = act ? csr[j] : 0;
    float4 s0 = *(const float4*)(asd + (size_t)s*32);
    float4 s1 = *(const float4*)(asd + (size_t)s*32 + 4);
    float4 s2 = *(const float4*)(asd + (size_t)s*32 + 8);
    float as[12] = {s0.x,s0.y,s0.z,s0.w, s1.x,s1.y,s1.z,s1.w, s2.x,s2.y,s2.z,s2.w};
    float w[12];
    #pragma unroll
    for (int h=0; h<12; ++h){
      float l = act ? lrelu(as[h] + ad[h]) : -1e30f;
      float m = l;
      #pragma unroll
      for (int off=32; off; off>>=1) m = fmaxf(m, __shfl_xor(m, off));
      float wv = act ? __expf(l - m) : 0.f;
      float ss = wv;
      #pragma unroll
      for (int off=32; off; off>>=1) ss += __shfl_xor(ss, off);
      w[h] = wv / ss;
    }
    if (act){
      float4 o0 = {w[0],w[1],w[2],w[3]};
      float4 o1 = {w[4],w[5],w[6],w[7]};
      float4 o2 = {w[8],w[9],w[10],w[11]};
      *(float4*)(alpha + (size_t)j*12)     = o0;
      *(float4*)(alpha + (size_t)j*12 + 4) = o1;
      *(float4*)(alpha + (size_t)j*12 + 8) = o2;
    }
  } else {
    float mx[12], ss[12];
    #pragma unroll
    for (int h=0;h<12;h++){ mx[h] = -1e30f; ss[h] = 0.f; }
    for (int j = r0 + lane; j < r1; j += 64){
      int s = csr[j];
      float4 s0 = *(const float4*)(asd + (size_t)s*32);
      float4 s1 = *(const float4*)(asd + (size_t)s*32 + 4);
      float4 s2 = *(const float4*)(asd + (size_t)s*32 + 8);
      float as[12] = {s0.x,s0.y,s0.z,s0.w, s1.x,s1.y,s1.z,s1.w, s2.x,s2.y,s2.z,s2.w};
      #pragma unroll
      for (int h=0;h<12;h++) mx[h] = fmaxf(mx[h], lrelu(as[h] + ad[h]));
    }
    #pragma unroll
    for (int h=0;h<12;h++){
      #pragma unroll
      for (int off=32; off; off>>=1) mx[h] = fmaxf(mx[h], __shfl_xor(mx[h], off));
    }
    for (int j = r0 + lane; j < r1; j += 64){
      int s = csr[j];
      float4 s0 = *(const float4*)(asd + (size_t)s*32);
      float4 s1 = *(const float4*)(asd + (size_t)s*32 + 4);
      float4 s2 = *(const float4*)(asd + (size_t)s*32 + 8);
      float as[12] = {s0.x,s0.y,s0.z,s0.w, s1.x,s1.y,s1.z,s1.w, s2.x,s2.y,s2.z,s2.w};
      float w[12];
      #pragma unroll
      for (int h=0;h<12;h++){ w[h] = __expf(lrelu(as[h]+ad[h]) - mx[h]); ss[h] += w[h]; }
      float4 o0 = {w[0],w[1],w[2],w[3]};
      float4 o1 = {w[4],w[5],w[6],w[7]};
      float4 o2 = {w[8],w[9],w[10],w[11]};
      *(float4*)(alpha + (size_t)j*12)     = o0;
      *(float4*)(alpha + (size_t)j*12 + 4) = o1;
      *(float4*)(alpha + (size_t)j*12 + 8) = o2;
    }
    float inv[12];
    #pragma unroll
    for (int h=0;h<12;h++){
      #pragma unroll
      for (int off=32; off; off>>=1) ss[h] += __shfl_xor(ss[h], off);
      inv[h] = 1.f / ss[h];
    }
    for (int j = r0 + lane; j < r1; j += 64){
      float4 o0 = *(const float4*)(alpha + (size_t)j*12);
      float4 o1 = *(const float4*)(alpha + (size_t)j*12 + 4);
      float4 o2 = *(const float4*)(alpha + (size_t)j*12 + 8);
      o0.x*=inv[0]; o0.y*=inv[1]; o0.z*=inv[2]; o0.w*=inv[3];
      o1.x*=inv[4]; o1.y*=inv[5]; o1.z*=inv[6]; o1.w*=inv[7];
      o2.x*=inv[8]; o2.y*=inv[9]; o2.z*=inv[10]; o2.w*=inv[11];
      *(float4*)(alpha + (size_t)j*12)     = o0;
      *(float4*)(alpha + (size_t)j*12 + 4) = o1;
      *(float4*)(alpha + (size_t)j*12 + 8) = o2;
    }
  }
}

// ---------- conv1: x-space aggregation + fused per-head MFMA transform (2 halves) ----------
// 16 dst/block, 16 lanes/dst; acc[12][8] f32/thread; LDS holds 6 heads at a time
__global__ __launch_bounds__(256) void agg1x_kernel(const int* __restrict__ rowptr,
    const int* __restrict__ csr, const unsigned short* __restrict__ xb,
    const float* __restrict__ alpha, const unsigned short* __restrict__ w1t,
    const float* __restrict__ bias, unsigned short* __restrict__ out1){
  constexpr int ROWE = 6*F_IN + 8;   // 776 ushorts (1552 B row)
  __shared__ unsigned short agg[16*ROWE];   // 24832 B
  int tid = threadIdx.x;
  int g = tid >> 4, t16 = tid & 15;
  int d = blockIdx.x*16 + g;
  int r0 = rowptr[d], r1 = rowptr[d+1];
  float acc[12][8];
  #pragma unroll
  for (int h=0;h<12;h++)
    #pragma unroll
    for (int i=0;i<8;i++) acc[h][i] = 0.f;

  float4 a0={0,0,0,0}, a1={0,0,0,0}, a2={0,0,0,0};
  ushort8 xv = {0,0,0,0,0,0,0,0};
  if (r0 < r1){
    int s = csr[r0];
    a0 = *(const float4*)(alpha + (size_t)r0*12);
    a1 = *(const float4*)(alpha + (size_t)r0*12 + 4);
    a2 = *(const float4*)(alpha + (size_t)r0*12 + 8);
    xv = *(const ushort8*)(xb + (size_t)s*F_IN + t16*8);
  }
  for (int j = r0; j < r1; ++j){
    float4 c0=a0, c1=a1, c2=a2; ushort8 cx=xv;
    if (j+1 < r1){
      int s = csr[j+1];
      a0 = *(const float4*)(alpha + (size_t)(j+1)*12);
      a1 = *(const float4*)(alpha + (size_t)(j+1)*12 + 4);
      a2 = *(const float4*)(alpha + (size_t)(j+1)*12 + 8);
      xv = *(const ushort8*)(xb + (size_t)s*F_IN + t16*8);
    }
    float xf[8];
    #pragma unroll
    for (int i=0;i<8;i++) xf[i] = bf2f((unsigned short)cx[i]);
    float aw[12] = {c0.x,c0.y,c0.z,c0.w, c1.x,c1.y,c1.z,c1.w, c2.x,c2.y,c2.z,c2.w};
    #pragma unroll
    for (int h=0;h<12;h++)
      #pragma unroll
      for (int i=0;i<8;i++) acc[h][i] += aw[h]*xf[i];
  }

  int wid = tid >> 6, lane = tid & 63;
  int r = lane & 15, q = lane >> 4;
  #pragma unroll
  for (int half = 0; half < 2; ++half){
    if (half) __syncthreads();   // previous half's reads done before overwrite
    #pragma unroll
    for (int h = 0; h < 6; ++h){
      ushort8 v;
      #pragma unroll
      for (int i=0;i<8;i++) v[i] = f2bf(acc[half*6+h][i]);
      *(ushort8*)(&agg[g*ROWE + h*F_IN + t16*8]) = v;
    }
    __syncthreads();
    // 12 mfma tiles (6 heads x 2 col-halves) over 4 waves
    for (int t = wid; t < 12; t += 4){
      int h = t >> 1, nb = t & 1;
      int hh = half*6 + h;
      f32x4 c = {0.f,0.f,0.f,0.f};
      #pragma unroll
      for (int kk=0; kk<4; ++kk){
        bf16x8 af = *(const bf16x8*)(&agg[r*ROWE + h*F_IN + kk*32 + q*8]);
        bf16x8 bq = *(const bf16x8*)(w1t + (size_t)(hh*32 + nb*16 + r)*F_IN + kk*32 + q*8);
        c = __builtin_amdgcn_mfma_f32_16x16x32_bf16(af, bq, c, 0,0,0);
      }
      int col = hh*32 + nb*16 + r;
      float bv = bias[col];
      #pragma unroll
      for (int rr=0; rr<4; ++rr){
        int od = blockIdx.x*16 + q*4 + rr;
        out1[(size_t)od*C1 + col] = f2bf(fmaxf(c[rr] + bv, 0.f));
      }
    }
  }
}

// ---------- per-node attention halves, conv2 ----------
__global__ void a2_kernel(const unsigned short* __restrict__ h2,
    const float* __restrict__ att_src, const float* __restrict__ att_dst,
    float* __restrict__ a_src, float* __restrict__ a_dst){
  int n = blockIdx.x*blockDim.x + threadIdx.x;
  if (n >= N_NODES) return;
  const unsigned short* hp = h2 + (size_t)n*C2;
  float s=0.f, d=0.f;
  #pragma unroll
  for (int k4=0;k4<16;k4++){
    ushort4 v = *(const ushort4*)(hp + k4*4);
    int b = k4*4;
    s += bf2f(v.x)*att_src[b] + bf2f(v.y)*att_src[b+1] + bf2f(v.z)*att_src[b+2] + bf2f(v.w)*att_src[b+3];
    d += bf2f(v.x)*att_dst[b] + bf2f(v.y)*att_dst[b+1] + bf2f(v.z)*att_dst[b+2] + bf2f(v.w)*att_dst[b+3];
  }
  a_src[n]=s; a_dst[n]=d;
}

// ---------- conv2: fused softmax + aggregation + mean-pool atomics ----------
#define AGG2_CH 64
__global__ __launch_bounds__(64) void agg2f_kernel(const int* __restrict__ rowptr,
    const int* __restrict__ csr, const unsigned short* __restrict__ h2,
    const float* __restrict__ asrc, const float* __restrict__ adst,
    const float* __restrict__ bias, const int* __restrict__ batch,
    float* __restrict__ pool){
  int d = blockIdx.x, tid = threadIdx.x;
  int r0 = rowptr[d], r1 = rowptr[d+1];
  float ad = adst[d];
  // phase A: online softmax stats over incoming edges
  float m = -1e30f, ss = 0.f;
  for (int j = r0 + tid; j < r1; j += 64){
    float l = lrelu(asrc[csr[j]] + ad);
    float mn = fmaxf(m, l);
    ss = ss*__expf(m - mn) + __expf(l - mn);
    m = mn;
  }
  #pragma unroll
  for (int off=32; off; off>>=1){
    float m2 = __shfl_xor(m, off);
    float s2 = __shfl_xor(ss, off);
    float mn = fmaxf(m, m2);
    ss = ss*__expf(m - mn) + s2*__expf(m2 - mn);
    m = mn;
  }
  float inv = 1.f / ss;
  // phase B: unnormalized aggregation
  __shared__ int   s_lds[AGG2_CH];
  __shared__ float red[3][C2];
  int grp = tid >> 4;
  int fb  = (tid & 15) * 4;
  float a0=0.f, a1=0.f, a2=0.f, a3=0.f;
  for (int c0 = r0; c0 < r1; c0 += AGG2_CH){
    int nc = min(AGG2_CH, r1 - c0);
    __syncthreads();
    if (tid < nc) s_lds[tid] = csr[c0 + tid];
    __syncthreads();
    for (int e = grp; e < nc; e += 4){
      int s = s_lds[e];
      float w = __expf(lrelu(asrc[s] + ad) - m);
      ushort4 hv = *(const ushort4*)(h2 + (size_t)s*C2 + fb);
      a0 += w*bf2f(hv.x); a1 += w*bf2f(hv.y); a2 += w*bf2f(hv.z); a3 += w*bf2f(hv.w);
    }
  }
  __syncthreads();
  if (grp > 0){
    float* p = &red[grp-1][fb];
    p[0]=a0; p[1]=a1; p[2]=a2; p[3]=a3;
  }
  __syncthreads();
  if (grp == 0){
    int g = batch[d];
    float4 b4 = *(const float4*)(bias + fb);
    float v0 = (a0 + red[0][fb+0] + red[1][fb+0] + red[2][fb+0])*inv + b4.x;
    float v1 = (a1 + red[0][fb+1] + red[1][fb+1] + red[2][fb+1])*inv + b4.y;
    float v2 = (a2 + red[0][fb+2] + red[1][fb+2] + red[2][fb+2])*inv + b4.z;
    float v3 = (a3 + red[0][fb+3] + red[1][fb+3] + red[2][fb+3])*inv + b4.w;
    atomicAdd(&pool[g*C2 + fb+0], v0);
    atomicAdd(&pool[g*C2 + fb+1], v1);
    atomicAdd(&pool[g*C2 + fb+2], v2);
    atomicAdd(&pool[g*C2 + fb+3], v3);
  }
}

__global__ void cnt_kernel(const int* __restrict__ batch, int* __restrict__ cnt){
  int n = blockIdx.x*blockDim.x + threadIdx.x;
  if (n < N_NODES) atomicAdd(&cnt[batch[n]], 1);
}
__global__ void finalize_kernel(const float* __restrict__ sums, const int* __restrict__ cnt,
                                float* __restrict__ out){
  int i = blockIdx.x*blockDim.x + threadIdx.x;
  if (i >= G_GRAPHS*C2) return;
  int g = i >> 6;
  out[i] = sums[i] / fmaxf((float)cnt[g], 1.f);
}

// ---------- launch ----------
extern "C" void kernel_launch(void* const* d_in, const int* in_sizes, int n_in,
                              void* d_out, int out_size, void* d_ws, size_t ws_size,
                              hipStream_t stream) {
  const float* x        = (const float*)d_in[0];
  const int*   ei       = (const int*)  d_in[1];
  const int*   batch    = (const int*)  d_in[2];
  const float* W1       = (const float*)d_in[3];
  const float* att_src1 = (const float*)d_in[4];
  const float* att_dst1 = (const float*)d_in[5];
  const float* bias1    = (const float*)d_in[6];
  const float* W2       = (const float*)d_in[7];
  const float* att_src2 = (const float*)d_in[8];
  const float* att_dst2 = (const float*)d_in[9];
  const float* bias2    = (const float*)d_in[10];
  float* out = (float*)d_out;

  char* ws = (char*)d_ws;
  size_t o = 0;
  auto alloc = [&](size_t bytes)->size_t{ size_t r=o; o=(o+bytes+255)&~(size_t)255; return r; };

  size_t xb_o     = alloc((size_t)N_NODES*F_IN*2);   // 12.8 MB
  size_t w1t_o    = alloc((size_t)C1*F_IN*2);
  size_t w2t_o    = alloc((size_t)C2*C1*2);
  size_t wab_o    = alloc((size_t)32*F_IN*2);
  size_t asd_o    = alloc((size_t)N_NODES*32*4);     // 6.4 MB (src:0-11, dst:12-23)
  size_t out1_o   = alloc((size_t)N_NODES*C1*2);     // 38.4 MB
  size_t h2_o     = alloc((size_t)N_NODES*C2*2);     // 6.4 MB
  size_t asrc2_o  = alloc((size_t)N_NODES*4);
  size_t adst2_o  = alloc((size_t)N_NODES*4);
  size_t alpha1_o = alloc((size_t)ETOT*H1*4);        // 40.8 MB
  size_t zero_beg = o;
  size_t counts_o = alloc((size_t)N_NODES*4);
  size_t pool_o   = alloc((size_t)G_GRAPHS*C2*4);
  size_t cnt_o    = alloc((size_t)G_GRAPHS*4);
  size_t zero_end = o;
  size_t rowptr_o = alloc((size_t)(N_NODES+1)*4);
  size_t bsum_o   = alloc((size_t)NBLK_SCAN*4);
  size_t cursor_o = alloc((size_t)N_NODES*4);
  size_t csr_o    = alloc((size_t)ETOT*4);

  unsigned short* xb    = (unsigned short*)(ws + xb_o);
  unsigned short* w1t   = (unsigned short*)(ws + w1t_o);
  unsigned short* w2t   = (unsigned short*)(ws + w2t_o);
  unsigned short* wab   = (unsigned short*)(ws + wab_o);
  float* asd    = (float*)(ws + asd_o);
  unsigned short* out1b = (unsigned short*)(ws + out1_o);
  unsigned short* h2b   = (unsigned short*)(ws + h2_o);
  float* asrc2  = (float*)(ws + asrc2_o);
  float* adst2  = (float*)(ws + adst2_o);
  float* alpha1 = (float*)(ws + alpha1_o);
  int*   counts = (int*)  (ws + counts_o);
  float* poolf  = (float*)(ws + pool_o);
  int*   cnt    = (int*)  (ws + cnt_o);
  int*   rowptr = (int*)  (ws + rowptr_o);
  int*   bsum   = (int*)  (ws + bsum_o);
  int*   cursor = (int*)  (ws + cursor_o);
  int*   csrsrc = (int*)  (ws + csr_o);

  hipMemsetAsync(ws + zero_beg, 0, zero_end - zero_beg, stream);

  const int TPB = 256;
  int egrid = (ETOT + TPB - 1)/TPB;

  // prep
  cast_x_kernel<<<(N_NODES*F_IN/4 + TPB-1)/TPB, TPB, 0, stream>>>(x, xb);
  transpose_w_kernel<<<(F_IN*C1 + TPB-1)/TPB, TPB, 0, stream>>>(W1, w1t, F_IN, C1);
  transpose_w_kernel<<<(C1*C2 + TPB-1)/TPB, TPB, 0, stream>>>(W2, w2t, C1, C2);
  wab_prep<<<(32*F_IN + TPB-1)/TPB, TPB, 0, stream>>>(W1, att_src1, att_dst1, wab);

  // CSR build
  count_kernel<<<egrid, TPB, 0, stream>>>(ei, counts);
  scan_pass1<<<NBLK_SCAN, SCAN_B, 0, stream>>>(counts, rowptr, bsum);
  scan_pass2<<<1, 64, 0, stream>>>(bsum);
  scan_pass3<<<(N_NODES + TPB)/TPB, TPB, 0, stream>>>(rowptr, bsum, cursor);
  scatter_kernel<<<egrid, TPB, 0, stream>>>(ei, cursor, csrsrc);

  // conv1: attention logits via tiny MFMA GEMM (f32 out), then alpha, then x-space agg
  gemm_mfma<128,32,32,32,true><<<dim3((N_NODES+127)/128, 1), 256, 0, stream>>>(xb, wab, asd, N_NODES, 32, F_IN);
  alpha1_kernel<<<N_NODES, 64, 0, stream>>>(rowptr, csrsrc, asd, alpha1);
  agg1x_kernel<<<N_NODES/16, 256, 0, stream>>>(rowptr, csrsrc, xb, alpha1, w1t, bias1, out1b);

  // conv2
  gemm_mfma<128,64,64,32,false><<<dim3((N_NODES+127)/128, 1), 256, 0, stream>>>(out1b, w2t, h2b, N_NODES, C2, C1);
  a2_kernel<<<(N_NODES + TPB-1)/TPB, TPB, 0, stream>>>(h2b, att_src2, att_dst2, asrc2, adst2);
  agg2f_kernel<<<N_NODES, 64, 0, stream>>>(rowptr, csrsrc, h2b, asrc2, adst2, bias2, batch, poolf);

  // pool finalize
  cnt_kernel<<<(N_NODES + TPB-1)/TPB, TPB, 0, stream>>>(batch, cnt);
  finalize_kernel<<<(G_GRAPHS*C2 + TPB-1)/TPB, TPB, 0, stream>>>(poolf, cnt, out);
}